// Round 4
// baseline (1827.698 us; speedup 1.0000x reference)
//
#include <hip/hip_runtime.h>
#include <hip/hip_bf16.h>
#include <math.h>

static constexpr int NNODE = 50000;
static constexpr int NEDGE = 600000;
static constexpr float EPSC   = 0.1f;
static constexpr float GAMMAC = 0.1f;

// ---- workspace layout (float offsets) ----
static constexpr long long O_DINV = 0;                        // NNODE
static constexpr long long O_DEG  = 50000;                    // NNODE
static constexpr long long O_FLAG = 100000;                   // 1 (int: 1 if edge_index is int64)
static constexpr long long O_AW1  = 100004;                   // 128*128
static constexpr long long O_G1T  = O_AW1 + 128*128;          // 128*128
static constexpr long long O_AW2  = O_G1T + 128*128;          // 64*64
static constexpr long long O_G2T  = O_AW2 + 64*64;            // 64*64
static constexpr long long O_H    = O_G2T + 64*64;            // NNODE*128
static constexpr long long O_G    = O_H + 50000LL*128;        // NNODE*128
static constexpr long long O_AGG  = O_G + 50000LL*128;        // NNODE*128

// ---- detect whether edge_index is int64 (odd words all zero) ----
__global__ __launch_bounds__(256) void sniff_kernel(const int* __restrict__ ei,
                                                    int* __restrict__ flag)
{
    __shared__ int nz;
    if (threadIdx.x == 0) nz = 0;
    __syncthreads();
    if (ei[2 * threadIdx.x + 1] != 0) atomicAdd(&nz, 1);
    __syncthreads();
    if (threadIdx.x == 0) flag[0] = (nz == 0) ? 1 : 0;
}

__device__ __forceinline__ int src_of(const int* ei, int e, int i64) {
    return i64 ? ei[2 * e] : ei[e];
}
__device__ __forceinline__ int dst_of(const int* ei, int e, int i64) {
    return i64 ? ei[2 * (NEDGE + e)] : ei[NEDGE + e];
}

// ---- weight prep: antisymmetrize W_a, transpose gcn weights (all fp32) ----
__global__ __launch_bounds__(256) void prep_kernel(
    const float* __restrict__ W_a1, const float* __restrict__ gcn1,
    const float* __restrict__ W_a2, const float* __restrict__ gcn2,
    float* __restrict__ ws)
{
    int j = blockIdx.x * 256 + threadIdx.x;
    if (j < 16384) { int r=j>>7, c=j&127;
                     ws[O_AW1+j] = W_a1[r*128+c] - W_a1[c*128+r] - (r==c?GAMMAC:0.f);
                     return; } j -= 16384;
    if (j < 16384) { int r=j>>7, c=j&127; ws[O_G1T+j] = gcn1[c*128+r]; return; } j -= 16384;
    if (j < 4096)  { int r=j>>6, c=j&63;
                     ws[O_AW2+j] = W_a2[r*64+c] - W_a2[c*64+r] - (r==c?GAMMAC:0.f);
                     return; } j -= 4096;
    if (j < 4096)  { int r=j>>6, c=j&63; ws[O_G2T+j] = gcn2[c*64+r]; return; }
}

// ---- degree / norm ----
__global__ __launch_bounds__(256) void deg_init_kernel(float* __restrict__ deg) {
    int i = blockIdx.x * 256 + threadIdx.x;
    if (i < NNODE) deg[i] = 1.0f;  // self loop
}
__global__ __launch_bounds__(256) void deg_count_kernel(const int* __restrict__ ei,
                                                        const int* __restrict__ flag,
                                                        float* __restrict__ deg) {
    int e = blockIdx.x * 256 + threadIdx.x;
    if (e < NEDGE) atomicAdd(&deg[dst_of(ei, e, flag[0])], 1.0f);
}
__global__ __launch_bounds__(256) void deg_inv_kernel(const float* __restrict__ deg,
                                                      float* __restrict__ dinv) {
    int i = blockIdx.x * 256 + threadIdx.x;
    if (i < NNODE) dinv[i] = rsqrtf(deg[i]);
}

__global__ __launch_bounds__(256) void zero_kernel(float* __restrict__ p, int n) {
    int i = blockIdx.x * 256 + threadIdx.x;
    if (i < n) p[i] = 0.0f;
}

// ---- GEMM: C[M,Nn] = epi(A[M,K] @ Bt[Nn,K]^T + bias) ----
// LOADACT==1: leaky_relu applied to A elements on load.
// EPI: 0 = none, 1 = leaky_relu, 2 = h + EPS*tanh(acc + agg + bias) (A is h, K==Nn)
template<int LOADACT, int EPI>
__global__ __launch_bounds__(256) void gemm_bt(
    const float* __restrict__ A, int lda,
    const float* __restrict__ Bt,
    const float* __restrict__ bias,
    const float* __restrict__ agg,
    float* __restrict__ C, int ldc,
    int M, int K, int Nn)
{
    constexpr int BM = 64, BN = 64, BK = 16;
    __shared__ float As[BK][BM + 4];
    __shared__ float Bs[BK][BN + 4];
    const int tid = threadIdx.x;
    const int tx = tid & 15, ty = tid >> 4;
    const int row0 = blockIdx.y * BM, col0 = blockIdx.x * BN;
    const int lk = tid & 15;   // k index within tile
    const int lr = tid >> 4;   // row/col group base

    float acc[4][4] = {{0.f,0.f,0.f,0.f},{0.f,0.f,0.f,0.f},{0.f,0.f,0.f,0.f},{0.f,0.f,0.f,0.f}};

    for (int k0 = 0; k0 < K; k0 += BK) {
        #pragma unroll
        for (int p = 0; p < 4; ++p) {
            int r  = lr + p * 16;
            int gr = row0 + r;
            float v = 0.f;
            if (gr < M) v = A[(long long)gr * lda + k0 + lk];
            if (LOADACT == 1) v = v > 0.f ? v : 0.01f * v;
            As[lk][r] = v;
            int c  = lr + p * 16;
            int gc = col0 + c;
            Bs[lk][c] = (gc < Nn) ? Bt[gc * K + k0 + lk] : 0.f;
        }
        __syncthreads();
        #pragma unroll
        for (int kk = 0; kk < BK; ++kk) {
            float4 a = *(const float4*)&As[kk][ty * 4];
            float4 b = *(const float4*)&Bs[kk][tx * 4];
            acc[0][0] += a.x*b.x; acc[0][1] += a.x*b.y; acc[0][2] += a.x*b.z; acc[0][3] += a.x*b.w;
            acc[1][0] += a.y*b.x; acc[1][1] += a.y*b.y; acc[1][2] += a.y*b.z; acc[1][3] += a.y*b.w;
            acc[2][0] += a.z*b.x; acc[2][1] += a.z*b.y; acc[2][2] += a.z*b.z; acc[2][3] += a.z*b.w;
            acc[3][0] += a.w*b.x; acc[3][1] += a.w*b.y; acc[3][2] += a.w*b.z; acc[3][3] += a.w*b.w;
        }
        __syncthreads();
    }

    #pragma unroll
    for (int i = 0; i < 4; ++i) {
        int r = row0 + ty * 4 + i;
        if (r >= M) continue;
        #pragma unroll
        for (int j = 0; j < 4; ++j) {
            int c = col0 + tx * 4 + j;
            if (c >= Nn) continue;
            float v = acc[i][j];
            if (bias) v += bias[c];
            if (EPI == 1) v = v > 0.f ? v : 0.01f * v;
            if (EPI == 2) {
                float h = A[(long long)r * lda + c];   // lda == K == Nn
                v = h + EPSC * tanhf(v + agg[(long long)r * ldc + c]);
            }
            C[(long long)r * ldc + c] = v;
        }
    }
}

// ---- edge scatter: agg[dst] += g[src] * dinv[src]*dinv[dst], incl. self loops ----
template<int HD>
__global__ __launch_bounds__(256) void scatter_kernel(
    const int* __restrict__ ei, const int* __restrict__ flag,
    const float* __restrict__ dinv,
    const float* __restrict__ g, float* __restrict__ agg)
{
    int gid = blockIdx.x * 256 + threadIdx.x;
    int e = gid / HD;
    int f = gid - e * HD;
    if (e >= NEDGE + NNODE) return;
    int s, d;
    if (e < NEDGE) { int i64 = flag[0]; s = src_of(ei, e, i64); d = dst_of(ei, e, i64); }
    else           { s = e - NEDGE; d = s; }
    float w = dinv[s] * dinv[d];
    atomicAdd(&agg[d * HD + f], g[s * HD + f] * w);
}

// ---- log_softmax over 40 classes, one wave per row, fp32 out ----
__global__ __launch_bounds__(256) void lsm_kernel(const float* __restrict__ z,
                                                  float* __restrict__ out)
{
    int gid = blockIdx.x * 256 + threadIdx.x;
    int row = gid >> 6;
    int lane = gid & 63;
    if (row >= NNODE) return;
    float v = (lane < 40) ? z[row * 40 + lane] : -1e30f;
    float m = v;
    #pragma unroll
    for (int o = 32; o > 0; o >>= 1) m = fmaxf(m, __shfl_xor(m, o));
    float e = (lane < 40) ? expf(v - m) : 0.f;
    float s = e;
    #pragma unroll
    for (int o = 32; o > 0; o >>= 1) s += __shfl_xor(s, o);
    float l = logf(s);
    if (lane < 40) out[row * 40 + lane] = v - m - l;
}

extern "C" void kernel_launch(void* const* d_in, const int* in_sizes, int n_in,
                              void* d_out, int out_size, void* d_ws, size_t ws_size,
                              hipStream_t stream) {
    const float* x     = (const float*)d_in[0];
    const int*   ei    = (const int*)d_in[1];
    const float* w_hid = (const float*)d_in[2];
    const float* b_hid = (const float*)d_in[3];
    const float* W_a1  = (const float*)d_in[4];
    const float* gcn1  = (const float*)d_in[5];
    const float* b_a1  = (const float*)d_in[6];
    const float* w2    = (const float*)d_in[7];
    const float* b2    = (const float*)d_in[8];
    const float* W_a2  = (const float*)d_in[9];
    const float* gcn2  = (const float*)d_in[10];
    const float* b_a2  = (const float*)d_in[11];
    const float* wfc   = (const float*)d_in[12];
    const float* bfc   = (const float*)d_in[13];
    float* ws = (float*)d_ws;
    float* out = (float*)d_out;

    float* deg   = ws + O_DEG;
    float* dinv  = ws + O_DINV;
    int*   flag  = (int*)(ws + O_FLAG);
    float* bufH  = ws + O_H;
    float* bufG  = ws + O_G;
    float* bufAg = ws + O_AGG;

    sniff_kernel<<<1, 256, 0, stream>>>(ei, flag);
    prep_kernel<<<160, 256, 0, stream>>>(W_a1, gcn1, W_a2, gcn2, ws);
    deg_init_kernel<<<(NNODE + 255) / 256, 256, 0, stream>>>(deg);
    deg_count_kernel<<<(NEDGE + 255) / 256, 256, 0, stream>>>(ei, flag, deg);
    deg_inv_kernel<<<(NNODE + 255) / 256, 256, 0, stream>>>(deg, dinv);

    dim3 grid1(2, (NNODE + 63) / 64);   // Nn=128
    dim3 grid2(1, (NNODE + 63) / 64);   // Nn<=64

    // h = leaky_relu(x @ w_hid^T + b_hid)  -> bufH
    gemm_bt<0, 1><<<grid1, 256, 0, stream>>>(
        x, 256, w_hid, b_hid, nullptr, bufH, 128, NNODE, 256, 128);

    // conv1: 3 iterations, ping-pong hc <-> ho
    float* hc = bufH;
    float* ho = bufG;
    for (int it = 0; it < 3; ++it) {
        // g = h @ gcn_w1  -> ho
        gemm_bt<0, 0><<<grid1, 256, 0, stream>>>(
            hc, 128, ws + O_G1T, nullptr, nullptr, ho, 128, NNODE, 128, 128);
        zero_kernel<<<(NNODE * 128 + 255) / 256, 256, 0, stream>>>(bufAg, NNODE * 128);
        scatter_kernel<128><<<((NEDGE + NNODE) * 128 + 255) / 256, 256, 0, stream>>>(
            ei, flag, dinv, ho, bufAg);
        // h_new = h + EPS*tanh(h@aW1^T + agg + b_a1) -> ho (g dead)
        gemm_bt<0, 2><<<grid1, 256, 0, stream>>>(
            hc, 128, ws + O_AW1, b_a1, bufAg, ho, 128, NNODE, 128, 128);
        float* t = hc; hc = ho; ho = t;
    }

    // h2 = leaky_relu(leaky_relu(h) @ w_hid2^T + b_hid2) -> ho
    gemm_bt<1, 1><<<grid2, 256, 0, stream>>>(
        hc, 128, w2, b2, nullptr, ho, 64, NNODE, 128, 64);
    float* h2 = ho;
    float* spare = hc;  // old h, dead now

    // conv2: 1 iteration
    gemm_bt<0, 0><<<grid2, 256, 0, stream>>>(
        h2, 64, ws + O_G2T, nullptr, nullptr, spare, 64, NNODE, 64, 64);   // g2 -> spare
    zero_kernel<<<(NNODE * 64 + 255) / 256, 256, 0, stream>>>(bufAg, NNODE * 64);
    scatter_kernel<64><<<((NEDGE + NNODE) * 64 + 255) / 256, 256, 0, stream>>>(
        ei, flag, dinv, spare, bufAg);
    gemm_bt<0, 2><<<grid2, 256, 0, stream>>>(
        h2, 64, ws + O_AW2, b_a2, bufAg, spare, 64, NNODE, 64, 64);  // h2_new -> spare

    // z = h2 @ w_fc^T + b_fc -> h2 buffer (stride 40)
    gemm_bt<0, 0><<<grid2, 256, 0, stream>>>(
        spare, 64, wfc, bfc, nullptr, h2, 40, NNODE, 64, 40);

    lsm_kernel<<<(NNODE * 64 + 255) / 256, 256, 0, stream>>>(h2, out);
}

// Round 5
// 1069.545 us; speedup vs baseline: 1.7089x; 1.7089x over previous
//
#include <hip/hip_runtime.h>
#include <hip/hip_bf16.h>
#include <math.h>

static constexpr int NNODE = 50000;
static constexpr int NEDGE = 600000;
static constexpr float EPSC   = 0.1f;
static constexpr float GAMMAC = 0.1f;

// ---- workspace layout (float-index offsets) ----
static constexpr long long O_DINV   = 0;                         // float NNODE
static constexpr long long O_DEGI   = 50000;                     // int   NNODE
static constexpr long long O_ROWPTR = 100000;                    // int   NNODE+1
static constexpr long long O_CURSOR = 150004;                    // int   NNODE
static constexpr long long O_COL    = 200004;                    // int   NEDGE
static constexpr long long O_WCSR   = 800004;                    // float NEDGE
static constexpr long long O_AW1    = 1400004;                   // 128*128
static constexpr long long O_G1T    = O_AW1 + 128*128;           // 128*128
static constexpr long long O_AW2    = O_G1T + 128*128;           // 64*64
static constexpr long long O_G2T    = O_AW2 + 64*64;             // 64*64
static constexpr long long O_H      = O_G2T + 64*64;             // NNODE*128
static constexpr long long O_G      = O_H + 50000LL*128;         // NNODE*128
static constexpr long long O_AGG    = O_G + 50000LL*128;         // NNODE*128

// ---- weight prep: antisymmetrize W_a, transpose gcn weights ----
__global__ __launch_bounds__(256) void prep_kernel(
    const float* __restrict__ W_a1, const float* __restrict__ gcn1,
    const float* __restrict__ W_a2, const float* __restrict__ gcn2,
    float* __restrict__ ws)
{
    int j = blockIdx.x * 256 + threadIdx.x;
    if (j < 16384) { int r=j>>7, c=j&127;
                     ws[O_AW1+j] = W_a1[r*128+c] - W_a1[c*128+r] - (r==c?GAMMAC:0.f);
                     return; } j -= 16384;
    if (j < 16384) { int r=j>>7, c=j&127; ws[O_G1T+j] = gcn1[c*128+r]; return; } j -= 16384;
    if (j < 4096)  { int r=j>>6, c=j&63;
                     ws[O_AW2+j] = W_a2[r*64+c] - W_a2[c*64+r] - (r==c?GAMMAC:0.f);
                     return; } j -= 4096;
    if (j < 4096)  { int r=j>>6, c=j&63; ws[O_G2T+j] = gcn2[c*64+r]; return; }
}

// ---- CSR build ----
__global__ __launch_bounds__(256) void zeroi_kernel(int* __restrict__ p, int n) {
    int i = blockIdx.x * 256 + threadIdx.x;
    if (i < n) p[i] = 0;
}
__global__ __launch_bounds__(256) void deg_count_kernel(const int* __restrict__ ei,
                                                        int* __restrict__ degi) {
    int e = blockIdx.x * 256 + threadIdx.x;
    if (e < NEDGE) atomicAdd(&degi[ei[NEDGE + e]], 1);
}
__global__ __launch_bounds__(256) void deg_inv_kernel(const int* __restrict__ degi,
                                                      float* __restrict__ dinv) {
    int i = blockIdx.x * 256 + threadIdx.x;
    if (i < NNODE) dinv[i] = rsqrtf(1.0f + (float)degi[i]);  // +1 self loop
}
// single-block exclusive scan over in-degrees -> rowptr, cursor
__global__ __launch_bounds__(256) void scan_kernel(const int* __restrict__ degi,
                                                   int* __restrict__ rowptr,
                                                   int* __restrict__ cursor) {
    __shared__ int smem[256];
    __shared__ int carry_s;
    if (threadIdx.x == 0) carry_s = 0;
    __syncthreads();
    for (int base = 0; base < NNODE; base += 256) {
        int i = base + threadIdx.x;
        int v = (i < NNODE) ? degi[i] : 0;
        smem[threadIdx.x] = v;
        __syncthreads();
        for (int off = 1; off < 256; off <<= 1) {
            int t = (threadIdx.x >= off) ? smem[threadIdx.x - off] : 0;
            __syncthreads();
            smem[threadIdx.x] += t;
            __syncthreads();
        }
        int excl = smem[threadIdx.x] - v;
        if (i < NNODE) { rowptr[i] = carry_s + excl; cursor[i] = carry_s + excl; }
        __syncthreads();
        if (threadIdx.x == 255) carry_s += smem[255];
        __syncthreads();
    }
    if (threadIdx.x == 0) rowptr[NNODE] = carry_s;
}
__global__ __launch_bounds__(256) void fill_kernel(const int* __restrict__ ei,
                                                   const float* __restrict__ dinv,
                                                   int* __restrict__ cursor,
                                                   int* __restrict__ col,
                                                   float* __restrict__ wcsr) {
    int e = blockIdx.x * 256 + threadIdx.x;
    if (e >= NEDGE) return;
    int s = ei[e], d = ei[NEDGE + e];
    int pos = atomicAdd(&cursor[d], 1);
    col[pos]  = s;
    wcsr[pos] = dinv[s] * dinv[d];
}

// ---- GEMM: C[M,Nn] = epi(A[M,K] @ Bt[Nn,K]^T + bias) ----
template<int LOADACT, int EPI>
__global__ __launch_bounds__(256) void gemm_bt(
    const float* __restrict__ A, int lda,
    const float* __restrict__ Bt,
    const float* __restrict__ bias,
    const float* __restrict__ agg,
    float* __restrict__ C, int ldc,
    int M, int K, int Nn)
{
    constexpr int BM = 64, BN = 64, BK = 16;
    __shared__ float As[BK][BM + 4];
    __shared__ float Bs[BK][BN + 4];
    const int tid = threadIdx.x;
    const int tx = tid & 15, ty = tid >> 4;
    const int row0 = blockIdx.y * BM, col0 = blockIdx.x * BN;
    const int lk = tid & 15;
    const int lr = tid >> 4;

    float acc[4][4] = {{0.f,0.f,0.f,0.f},{0.f,0.f,0.f,0.f},{0.f,0.f,0.f,0.f},{0.f,0.f,0.f,0.f}};

    for (int k0 = 0; k0 < K; k0 += BK) {
        #pragma unroll
        for (int p = 0; p < 4; ++p) {
            int r  = lr + p * 16;
            int gr = row0 + r;
            float v = 0.f;
            if (gr < M) v = A[(long long)gr * lda + k0 + lk];
            if (LOADACT == 1) v = v > 0.f ? v : 0.01f * v;
            As[lk][r] = v;
            int c  = lr + p * 16;
            int gc = col0 + c;
            Bs[lk][c] = (gc < Nn) ? Bt[gc * K + k0 + lk] : 0.f;
        }
        __syncthreads();
        #pragma unroll
        for (int kk = 0; kk < BK; ++kk) {
            float4 a = *(const float4*)&As[kk][ty * 4];
            float4 b = *(const float4*)&Bs[kk][tx * 4];
            acc[0][0] += a.x*b.x; acc[0][1] += a.x*b.y; acc[0][2] += a.x*b.z; acc[0][3] += a.x*b.w;
            acc[1][0] += a.y*b.x; acc[1][1] += a.y*b.y; acc[1][2] += a.y*b.z; acc[1][3] += a.y*b.w;
            acc[2][0] += a.z*b.x; acc[2][1] += a.z*b.y; acc[2][2] += a.z*b.z; acc[2][3] += a.z*b.w;
            acc[3][0] += a.w*b.x; acc[3][1] += a.w*b.y; acc[3][2] += a.w*b.z; acc[3][3] += a.w*b.w;
        }
        __syncthreads();
    }

    #pragma unroll
    for (int i = 0; i < 4; ++i) {
        int r = row0 + ty * 4 + i;
        if (r >= M) continue;
        #pragma unroll
        for (int j = 0; j < 4; ++j) {
            int c = col0 + tx * 4 + j;
            if (c >= Nn) continue;
            float v = acc[i][j];
            if (bias) v += bias[c];
            if (EPI == 1) v = v > 0.f ? v : 0.01f * v;
            if (EPI == 2) {
                float h = A[(long long)r * lda + c];   // lda == K == Nn
                v = h + EPSC * tanhf(v + agg[(long long)r * ldc + c]);
            }
            C[(long long)r * ldc + c] = v;
        }
    }
}

// ---- CSR gather: one wave per node, no atomics, includes self loop ----
template<int HD>
__global__ __launch_bounds__(256) void gather_kernel(
    const int* __restrict__ rowptr, const int* __restrict__ col,
    const float* __restrict__ wcsr, const float* __restrict__ dinv,
    const float* __restrict__ g, float* __restrict__ agg)
{
    int wave = (blockIdx.x * 256 + threadIdx.x) >> 6;
    int lane = threadIdx.x & 63;
    if (wave >= NNODE) return;
    const int n = wave;
    const int r0 = rowptr[n], r1 = rowptr[n + 1];
    const float wself = dinv[n] * dinv[n];

    float acc0, acc1 = 0.f;
    if (HD == 128) {
        float2 gs = *(const float2*)&g[(long long)n * 128 + lane * 2];
        acc0 = gs.x * wself; acc1 = gs.y * wself;
    } else {
        acc0 = g[(long long)n * 64 + lane] * wself;
    }

    for (int base = r0; base < r1; base += 64) {
        int idx = base + lane;
        int cs = 0; float cw = 0.f;
        if (idx < r1) { cs = col[idx]; cw = wcsr[idx]; }
        int cnt = min(64, r1 - base);
        for (int j = 0; j < cnt; ++j) {
            int   s = __shfl(cs, j);
            float w = __shfl(cw, j);
            if (HD == 128) {
                float2 gv = *(const float2*)&g[(long long)s * 128 + lane * 2];
                acc0 += gv.x * w; acc1 += gv.y * w;
            } else {
                acc0 += g[(long long)s * 64 + lane] * w;
            }
        }
    }

    if (HD == 128) {
        float2 o; o.x = acc0; o.y = acc1;
        *(float2*)&agg[(long long)n * 128 + lane * 2] = o;
    } else {
        agg[(long long)n * 64 + lane] = acc0;
    }
}

// ---- log_softmax over 40 classes, one wave per row, fp32 out ----
__global__ __launch_bounds__(256) void lsm_kernel(const float* __restrict__ z,
                                                  float* __restrict__ out)
{
    int gid = blockIdx.x * 256 + threadIdx.x;
    int row = gid >> 6;
    int lane = gid & 63;
    if (row >= NNODE) return;
    float v = (lane < 40) ? z[row * 40 + lane] : -1e30f;
    float m = v;
    #pragma unroll
    for (int o = 32; o > 0; o >>= 1) m = fmaxf(m, __shfl_xor(m, o));
    float e = (lane < 40) ? expf(v - m) : 0.f;
    float s = e;
    #pragma unroll
    for (int o = 32; o > 0; o >>= 1) s += __shfl_xor(s, o);
    float l = logf(s);
    if (lane < 40) out[row * 40 + lane] = v - m - l;
}

extern "C" void kernel_launch(void* const* d_in, const int* in_sizes, int n_in,
                              void* d_out, int out_size, void* d_ws, size_t ws_size,
                              hipStream_t stream) {
    const float* x     = (const float*)d_in[0];
    const int*   ei    = (const int*)d_in[1];
    const float* w_hid = (const float*)d_in[2];
    const float* b_hid = (const float*)d_in[3];
    const float* W_a1  = (const float*)d_in[4];
    const float* gcn1  = (const float*)d_in[5];
    const float* b_a1  = (const float*)d_in[6];
    const float* w2    = (const float*)d_in[7];
    const float* b2    = (const float*)d_in[8];
    const float* W_a2  = (const float*)d_in[9];
    const float* gcn2  = (const float*)d_in[10];
    const float* b_a2  = (const float*)d_in[11];
    const float* wfc   = (const float*)d_in[12];
    const float* bfc   = (const float*)d_in[13];
    float* ws = (float*)d_ws;
    float* out = (float*)d_out;

    float* dinv   = ws + O_DINV;
    int*   degi   = (int*)(ws + O_DEGI);
    int*   rowptr = (int*)(ws + O_ROWPTR);
    int*   cursor = (int*)(ws + O_CURSOR);
    int*   col    = (int*)(ws + O_COL);
    float* wcsr   = ws + O_WCSR;
    float* bufH   = ws + O_H;
    float* bufG   = ws + O_G;
    float* bufAg  = ws + O_AGG;

    // CSR build
    prep_kernel<<<160, 256, 0, stream>>>(W_a1, gcn1, W_a2, gcn2, ws);
    zeroi_kernel<<<(NNODE + 255) / 256, 256, 0, stream>>>(degi, NNODE);
    deg_count_kernel<<<(NEDGE + 255) / 256, 256, 0, stream>>>(ei, degi);
    deg_inv_kernel<<<(NNODE + 255) / 256, 256, 0, stream>>>(degi, dinv);
    scan_kernel<<<1, 256, 0, stream>>>(degi, rowptr, cursor);
    fill_kernel<<<(NEDGE + 255) / 256, 256, 0, stream>>>(ei, dinv, cursor, col, wcsr);

    dim3 grid1(2, (NNODE + 63) / 64);   // Nn=128
    dim3 grid2(1, (NNODE + 63) / 64);   // Nn<=64
    int gatherBlocks = (NNODE * 64 + 255) / 256;

    // h = leaky_relu(x @ w_hid^T + b_hid)  -> bufH
    gemm_bt<0, 1><<<grid1, 256, 0, stream>>>(
        x, 256, w_hid, b_hid, nullptr, bufH, 128, NNODE, 256, 128);

    // conv1: 3 iterations, ping-pong hc <-> ho
    float* hc = bufH;
    float* ho = bufG;
    for (int it = 0; it < 3; ++it) {
        gemm_bt<0, 0><<<grid1, 256, 0, stream>>>(
            hc, 128, ws + O_G1T, nullptr, nullptr, ho, 128, NNODE, 128, 128);
        gather_kernel<128><<<gatherBlocks, 256, 0, stream>>>(
            rowptr, col, wcsr, dinv, ho, bufAg);
        gemm_bt<0, 2><<<grid1, 256, 0, stream>>>(
            hc, 128, ws + O_AW1, b_a1, bufAg, ho, 128, NNODE, 128, 128);
        float* t = hc; hc = ho; ho = t;
    }

    // h2 = leaky_relu(leaky_relu(h) @ w_hid2^T + b_hid2) -> ho
    gemm_bt<1, 1><<<grid2, 256, 0, stream>>>(
        hc, 128, w2, b2, nullptr, ho, 64, NNODE, 128, 64);
    float* h2 = ho;
    float* spare = hc;

    // conv2: 1 iteration
    gemm_bt<0, 0><<<grid2, 256, 0, stream>>>(
        h2, 64, ws + O_G2T, nullptr, nullptr, spare, 64, NNODE, 64, 64);
    gather_kernel<64><<<gatherBlocks, 256, 0, stream>>>(
        rowptr, col, wcsr, dinv, spare, bufAg);
    gemm_bt<0, 2><<<grid2, 256, 0, stream>>>(
        h2, 64, ws + O_AW2, b_a2, bufAg, spare, 64, NNODE, 64, 64);

    // z = h2 @ w_fc^T + b_fc
    gemm_bt<0, 0><<<grid2, 256, 0, stream>>>(
        spare, 64, wfc, bfc, nullptr, h2, 40, NNODE, 64, 40);

    lsm_kernel<<<(NNODE * 64 + 255) / 256, 256, 0, stream>>>(h2, out);
}

// Round 6
// 977.857 us; speedup vs baseline: 1.8691x; 1.0938x over previous
//
#include <hip/hip_runtime.h>
#include <hip/hip_bf16.h>
#include <math.h>

static constexpr int NNODE = 50000;
static constexpr int NEDGE = 600000;
static constexpr float EPSC   = 0.1f;
static constexpr float GAMMAC = 0.1f;

// ---- workspace layout (float-index offsets) ----
static constexpr long long O_DINV   = 0;                         // float NNODE
static constexpr long long O_DEGI   = 50000;                     // int   NNODE
static constexpr long long O_ROWPTR = 100000;                    // int   NNODE+1
static constexpr long long O_CURSOR = 150004;                    // int   NNODE
static constexpr long long O_COL    = 200004;                    // int   NEDGE
static constexpr long long O_WCSR   = 800004;                    // float NEDGE
static constexpr long long O_AW1    = 1400004;                   // 128*128
static constexpr long long O_G1T    = O_AW1 + 128*128;           // 128*128
static constexpr long long O_AW2    = O_G1T + 128*128;           // 64*64
static constexpr long long O_G2T    = O_AW2 + 64*64;             // 64*64
static constexpr long long O_H      = O_G2T + 64*64;             // NNODE*128
static constexpr long long O_G      = O_H + 50000LL*128;         // NNODE*128
static constexpr long long O_AGG    = O_G + 50000LL*128;         // NNODE*128

// ---- weight prep: antisymmetrize W_a, transpose gcn weights ----
__global__ __launch_bounds__(256) void prep_kernel(
    const float* __restrict__ W_a1, const float* __restrict__ gcn1,
    const float* __restrict__ W_a2, const float* __restrict__ gcn2,
    float* __restrict__ ws)
{
    int j = blockIdx.x * 256 + threadIdx.x;
    if (j < 16384) { int r=j>>7, c=j&127;
                     ws[O_AW1+j] = W_a1[r*128+c] - W_a1[c*128+r] - (r==c?GAMMAC:0.f);
                     return; } j -= 16384;
    if (j < 16384) { int r=j>>7, c=j&127; ws[O_G1T+j] = gcn1[c*128+r]; return; } j -= 16384;
    if (j < 4096)  { int r=j>>6, c=j&63;
                     ws[O_AW2+j] = W_a2[r*64+c] - W_a2[c*64+r] - (r==c?GAMMAC:0.f);
                     return; } j -= 4096;
    if (j < 4096)  { int r=j>>6, c=j&63; ws[O_G2T+j] = gcn2[c*64+r]; return; }
}

// ---- CSR build ----
__global__ __launch_bounds__(256) void zeroi_kernel(int* __restrict__ p, int n) {
    int i = blockIdx.x * 256 + threadIdx.x;
    if (i < n) p[i] = 0;
}
__global__ __launch_bounds__(256) void deg_count_kernel(const int* __restrict__ ei,
                                                        int* __restrict__ degi) {
    int e = blockIdx.x * 256 + threadIdx.x;
    if (e < NEDGE) atomicAdd(&degi[ei[NEDGE + e]], 1);
}
__global__ __launch_bounds__(256) void deg_inv_kernel(const int* __restrict__ degi,
                                                      float* __restrict__ dinv) {
    int i = blockIdx.x * 256 + threadIdx.x;
    if (i < NNODE) dinv[i] = rsqrtf(1.0f + (float)degi[i]);  // +1 self loop
}
// single-block scan: 256 threads x ~196-elem serial chunks, shuffle scan of totals.
// ~2 passes over 200 KB (L2-hot) + 2 barriers, vs the old ~3000-barrier version.
__global__ __launch_bounds__(256) void scan_kernel(const int* __restrict__ degi,
                                                   int* __restrict__ rowptr,
                                                   int* __restrict__ cursor) {
    constexpr int CH = (NNODE + 255) / 256;   // 196
    const int t = threadIdx.x;
    const int start = t * CH;
    const int end   = min(start + CH, NNODE);

    int sum = 0;
    for (int i = start; i < end; ++i) sum += degi[i];

    // exclusive scan of per-thread sums across 256 threads
    const int lane = t & 63, w = t >> 6;
    int v = sum;
    #pragma unroll
    for (int off = 1; off < 64; off <<= 1) {
        int u = __shfl_up(v, off);
        if (lane >= off) v += u;
    }
    __shared__ int wsum[4];
    if (lane == 63) wsum[w] = v;
    __syncthreads();
    int woff = 0;
    for (int i = 0; i < w; ++i) woff += wsum[i];
    int run = woff + v - sum;   // exclusive prefix for this thread's chunk

    for (int i = start; i < end; ++i) {
        rowptr[i] = run; cursor[i] = run;
        run += degi[i];
    }
    if (t == 255) rowptr[NNODE] = run;
}
__global__ __launch_bounds__(256) void fill_kernel(const int* __restrict__ ei,
                                                   const float* __restrict__ dinv,
                                                   int* __restrict__ cursor,
                                                   int* __restrict__ col,
                                                   float* __restrict__ wcsr) {
    int e = blockIdx.x * 256 + threadIdx.x;
    if (e >= NEDGE) return;
    int s = ei[e], d = ei[NEDGE + e];
    int pos = atomicAdd(&cursor[d], 1);
    col[pos]  = s;
    wcsr[pos] = dinv[s] * dinv[d];
}

// ---- GEMM: C[M,Nn] = epi(A[M,K] @ Bt[Nn,K]^T + bias) ----
template<int LOADACT, int EPI>
__global__ __launch_bounds__(256) void gemm_bt(
    const float* __restrict__ A, int lda,
    const float* __restrict__ Bt,
    const float* __restrict__ bias,
    const float* __restrict__ agg,
    float* __restrict__ C, int ldc,
    int M, int K, int Nn)
{
    constexpr int BM = 64, BN = 64, BK = 16;
    __shared__ float As[BK][BM + 4];
    __shared__ float Bs[BK][BN + 4];
    const int tid = threadIdx.x;
    const int tx = tid & 15, ty = tid >> 4;
    const int row0 = blockIdx.y * BM, col0 = blockIdx.x * BN;
    const int lk = tid & 15;
    const int lr = tid >> 4;

    float acc[4][4] = {{0.f,0.f,0.f,0.f},{0.f,0.f,0.f,0.f},{0.f,0.f,0.f,0.f},{0.f,0.f,0.f,0.f}};

    for (int k0 = 0; k0 < K; k0 += BK) {
        #pragma unroll
        for (int p = 0; p < 4; ++p) {
            int r  = lr + p * 16;
            int gr = row0 + r;
            float v = 0.f;
            if (gr < M) v = A[(long long)gr * lda + k0 + lk];
            if (LOADACT == 1) v = v > 0.f ? v : 0.01f * v;
            As[lk][r] = v;
            int c  = lr + p * 16;
            int gc = col0 + c;
            Bs[lk][c] = (gc < Nn) ? Bt[gc * K + k0 + lk] : 0.f;
        }
        __syncthreads();
        #pragma unroll
        for (int kk = 0; kk < BK; ++kk) {
            float4 a = *(const float4*)&As[kk][ty * 4];
            float4 b = *(const float4*)&Bs[kk][tx * 4];
            acc[0][0] += a.x*b.x; acc[0][1] += a.x*b.y; acc[0][2] += a.x*b.z; acc[0][3] += a.x*b.w;
            acc[1][0] += a.y*b.x; acc[1][1] += a.y*b.y; acc[1][2] += a.y*b.z; acc[1][3] += a.y*b.w;
            acc[2][0] += a.z*b.x; acc[2][1] += a.z*b.y; acc[2][2] += a.z*b.z; acc[2][3] += a.z*b.w;
            acc[3][0] += a.w*b.x; acc[3][1] += a.w*b.y; acc[3][2] += a.w*b.z; acc[3][3] += a.w*b.w;
        }
        __syncthreads();
    }

    #pragma unroll
    for (int i = 0; i < 4; ++i) {
        int r = row0 + ty * 4 + i;
        if (r >= M) continue;
        #pragma unroll
        for (int j = 0; j < 4; ++j) {
            int c = col0 + tx * 4 + j;
            if (c >= Nn) continue;
            float v = acc[i][j];
            if (bias) v += bias[c];
            if (EPI == 1) v = v > 0.f ? v : 0.01f * v;
            if (EPI == 2) {
                float h = A[(long long)r * lda + c];   // lda == K == Nn
                v = h + EPSC * tanhf(v + agg[(long long)r * ldc + c]);
            }
            C[(long long)r * ldc + c] = v;
        }
    }
}

// ---- CSR gather: one wave per node, no atomics, includes self loop ----
template<int HD>
__global__ __launch_bounds__(256) void gather_kernel(
    const int* __restrict__ rowptr, const int* __restrict__ col,
    const float* __restrict__ wcsr, const float* __restrict__ dinv,
    const float* __restrict__ g, float* __restrict__ agg)
{
    int wave = (blockIdx.x * 256 + threadIdx.x) >> 6;
    int lane = threadIdx.x & 63;
    if (wave >= NNODE) return;
    const int n = wave;
    const int r0 = rowptr[n], r1 = rowptr[n + 1];
    const float wself = dinv[n] * dinv[n];

    float acc0, acc1 = 0.f;
    if (HD == 128) {
        float2 gs = *(const float2*)&g[(long long)n * 128 + lane * 2];
        acc0 = gs.x * wself; acc1 = gs.y * wself;
    } else {
        acc0 = g[(long long)n * 64 + lane] * wself;
    }

    for (int base = r0; base < r1; base += 64) {
        int idx = base + lane;
        int cs = 0; float cw = 0.f;
        if (idx < r1) { cs = col[idx]; cw = wcsr[idx]; }
        int cnt = min(64, r1 - base);
        for (int j = 0; j < cnt; ++j) {
            int   s = __shfl(cs, j);
            float w = __shfl(cw, j);
            if (HD == 128) {
                float2 gv = *(const float2*)&g[(long long)s * 128 + lane * 2];
                acc0 += gv.x * w; acc1 += gv.y * w;
            } else {
                acc0 += g[(long long)s * 64 + lane] * w;
            }
        }
    }

    if (HD == 128) {
        float2 o; o.x = acc0; o.y = acc1;
        *(float2*)&agg[(long long)n * 128 + lane * 2] = o;
    } else {
        agg[(long long)n * 64 + lane] = acc0;
    }
}

// ---- log_softmax over 40 classes, one wave per row, fp32 out ----
__global__ __launch_bounds__(256) void lsm_kernel(const float* __restrict__ z,
                                                  float* __restrict__ out)
{
    int gid = blockIdx.x * 256 + threadIdx.x;
    int row = gid >> 6;
    int lane = gid & 63;
    if (row >= NNODE) return;
    float v = (lane < 40) ? z[row * 40 + lane] : -1e30f;
    float m = v;
    #pragma unroll
    for (int o = 32; o > 0; o >>= 1) m = fmaxf(m, __shfl_xor(m, o));
    float e = (lane < 40) ? expf(v - m) : 0.f;
    float s = e;
    #pragma unroll
    for (int o = 32; o > 0; o >>= 1) s += __shfl_xor(s, o);
    float l = logf(s);
    if (lane < 40) out[row * 40 + lane] = v - m - l;
}

extern "C" void kernel_launch(void* const* d_in, const int* in_sizes, int n_in,
                              void* d_out, int out_size, void* d_ws, size_t ws_size,
                              hipStream_t stream) {
    const float* x     = (const float*)d_in[0];
    const int*   ei    = (const int*)d_in[1];
    const float* w_hid = (const float*)d_in[2];
    const float* b_hid = (const float*)d_in[3];
    const float* W_a1  = (const float*)d_in[4];
    const float* gcn1  = (const float*)d_in[5];
    const float* b_a1  = (const float*)d_in[6];
    const float* w2    = (const float*)d_in[7];
    const float* b2    = (const float*)d_in[8];
    const float* W_a2  = (const float*)d_in[9];
    const float* gcn2  = (const float*)d_in[10];
    const float* b_a2  = (const float*)d_in[11];
    const float* wfc   = (const float*)d_in[12];
    const float* bfc   = (const float*)d_in[13];
    float* ws = (float*)d_ws;
    float* out = (float*)d_out;

    float* dinv   = ws + O_DINV;
    int*   degi   = (int*)(ws + O_DEGI);
    int*   rowptr = (int*)(ws + O_ROWPTR);
    int*   cursor = (int*)(ws + O_CURSOR);
    int*   col    = (int*)(ws + O_COL);
    float* wcsr   = ws + O_WCSR;
    float* bufH   = ws + O_H;
    float* bufG   = ws + O_G;
    float* bufAg  = ws + O_AGG;

    // CSR build
    prep_kernel<<<160, 256, 0, stream>>>(W_a1, gcn1, W_a2, gcn2, ws);
    zeroi_kernel<<<(NNODE + 255) / 256, 256, 0, stream>>>(degi, NNODE);
    deg_count_kernel<<<(NEDGE + 255) / 256, 256, 0, stream>>>(ei, degi);
    deg_inv_kernel<<<(NNODE + 255) / 256, 256, 0, stream>>>(degi, dinv);
    scan_kernel<<<1, 256, 0, stream>>>(degi, rowptr, cursor);
    fill_kernel<<<(NEDGE + 255) / 256, 256, 0, stream>>>(ei, dinv, cursor, col, wcsr);

    dim3 grid1(2, (NNODE + 63) / 64);   // Nn=128
    dim3 grid2(1, (NNODE + 63) / 64);   // Nn<=64
    int gatherBlocks = (NNODE * 64 + 255) / 256;

    // h = leaky_relu(x @ w_hid^T + b_hid)  -> bufH
    gemm_bt<0, 1><<<grid1, 256, 0, stream>>>(
        x, 256, w_hid, b_hid, nullptr, bufH, 128, NNODE, 256, 128);

    // conv1: 3 iterations, ping-pong hc <-> ho
    float* hc = bufH;
    float* ho = bufG;
    for (int it = 0; it < 3; ++it) {
        gemm_bt<0, 0><<<grid1, 256, 0, stream>>>(
            hc, 128, ws + O_G1T, nullptr, nullptr, ho, 128, NNODE, 128, 128);
        gather_kernel<128><<<gatherBlocks, 256, 0, stream>>>(
            rowptr, col, wcsr, dinv, ho, bufAg);
        gemm_bt<0, 2><<<grid1, 256, 0, stream>>>(
            hc, 128, ws + O_AW1, b_a1, bufAg, ho, 128, NNODE, 128, 128);
        float* t = hc; hc = ho; ho = t;
    }

    // h2 = leaky_relu(leaky_relu(h) @ w_hid2^T + b_hid2) -> ho
    gemm_bt<1, 1><<<grid2, 256, 0, stream>>>(
        hc, 128, w2, b2, nullptr, ho, 64, NNODE, 128, 64);
    float* h2 = ho;
    float* spare = hc;

    // conv2: 1 iteration
    gemm_bt<0, 0><<<grid2, 256, 0, stream>>>(
        h2, 64, ws + O_G2T, nullptr, nullptr, spare, 64, NNODE, 64, 64);
    gather_kernel<64><<<gatherBlocks, 256, 0, stream>>>(
        rowptr, col, wcsr, dinv, spare, bufAg);
    gemm_bt<0, 2><<<grid2, 256, 0, stream>>>(
        h2, 64, ws + O_AW2, b_a2, bufAg, spare, 64, NNODE, 64, 64);

    // z = h2 @ w_fc^T + b_fc
    gemm_bt<0, 0><<<grid2, 256, 0, stream>>>(
        spare, 64, wfc, bfc, nullptr, h2, 40, NNODE, 64, 40);

    lsm_kernel<<<(NNODE * 64 + 255) / 256, 256, 0, stream>>>(h2, out);
}

// Round 7
// 678.412 us; speedup vs baseline: 2.6941x; 1.4414x over previous
//
#include <hip/hip_runtime.h>
#include <hip/hip_bf16.h>
#include <math.h>

typedef unsigned short u16;
using short8 = __attribute__((ext_vector_type(8))) short;
using f32x4  = __attribute__((ext_vector_type(4))) float;

static constexpr int NNODE = 50000;
static constexpr int NEDGE = 600000;
static constexpr float EPSC   = 0.1f;
static constexpr float GAMMAC = 0.1f;

// ---- workspace layout (float-index offsets) ----
static constexpr long long O_DINV   = 0;                         // float 50000
static constexpr long long O_DEGI   = 50000;                     // int 50000
static constexpr long long O_ROWPTR = 100000;                    // int 50001
static constexpr long long O_CURSOR = 150004;                    // int 50000
static constexpr long long O_PSUM   = 200004;                    // int 256
static constexpr long long O_COL    = 200260;                    // int 600000
static constexpr long long O_WCSR   = 800260;                    // float 600000
// bf16 weights (float slots = bf16count/2)
static constexpr long long O_WHB    = 1400260;                   // 32768 bf16
static constexpr long long O_G1TB   = O_WHB  + 16384;            // 16384 bf16
static constexpr long long O_AW1B   = O_G1TB + 8192;             // 16384 bf16
static constexpr long long O_W2B    = O_AW1B + 8192;             // 8192 bf16
static constexpr long long O_AW2B   = O_W2B  + 4096;             // 4096 bf16
static constexpr long long O_G2TB   = O_AW2B + 2048;             // 4096 bf16
static constexpr long long O_WFCB   = O_G2TB + 2048;             // 2560 bf16
// big buffers
static constexpr long long O_HF0    = 1450000;                   // float 6.4M
static constexpr long long O_HF1    = O_HF0 + 6400000;           // float 6.4M
static constexpr long long O_AGG    = O_HF1 + 6400000;           // float 6.4M
static constexpr long long O_GF     = O_AGG + 6400000;           // float 6.4M (also xb bf16)
static constexpr long long O_HB0    = O_GF  + 6400000;           // bf16 6.4M (3.2M floats)
static constexpr long long O_HB1    = O_HB0 + 3200000;           // bf16 6.4M

__device__ __forceinline__ float bf2f(u16 u) {
    return __uint_as_float(((unsigned)u) << 16);
}
__device__ __forceinline__ u16 f2bf(float f) {
    unsigned u = __float_as_uint(f);
    return (u16)((u + 0x7FFFu + ((u >> 16) & 1u)) >> 16);
}

// ---- x fp32 -> bf16 ----
__global__ __launch_bounds__(256) void cvt_kernel(const float* __restrict__ in,
                                                  u16* __restrict__ out, int n4) {
    int i = blockIdx.x * 256 + threadIdx.x;
    if (i >= n4) return;
    float4 f = ((const float4*)in)[i];
    ushort4 o;
    o.x = f2bf(f.x); o.y = f2bf(f.y); o.z = f2bf(f.z); o.w = f2bf(f.w);
    ((ushort4*)out)[i] = o;
}

// ---- weight prep: antisymmetrize / transpose, all to bf16 ----
__global__ __launch_bounds__(256) void prep_kernel(
    const float* __restrict__ w_hid, const float* __restrict__ W_a1,
    const float* __restrict__ gcn1,  const float* __restrict__ w2,
    const float* __restrict__ W_a2,  const float* __restrict__ gcn2,
    const float* __restrict__ wfc,   float* __restrict__ ws)
{
    int j = blockIdx.x * 256 + threadIdx.x;
    if (j < 32768) { ((u16*)(ws+O_WHB))[j] = f2bf(w_hid[j]); return; } j -= 32768;
    if (j < 16384) { int r=j>>7, c=j&127; ((u16*)(ws+O_G1TB))[j] = f2bf(gcn1[c*128+r]); return; } j -= 16384;
    if (j < 16384) { int r=j>>7, c=j&127;
                     ((u16*)(ws+O_AW1B))[j] = f2bf(W_a1[r*128+c] - W_a1[c*128+r] - (r==c?GAMMAC:0.f));
                     return; } j -= 16384;
    if (j < 8192)  { ((u16*)(ws+O_W2B))[j] = f2bf(w2[j]); return; } j -= 8192;
    if (j < 4096)  { int r=j>>6, c=j&63;
                     ((u16*)(ws+O_AW2B))[j] = f2bf(W_a2[r*64+c] - W_a2[c*64+r] - (r==c?GAMMAC:0.f));
                     return; } j -= 4096;
    if (j < 4096)  { int r=j>>6, c=j&63; ((u16*)(ws+O_G2TB))[j] = f2bf(gcn2[c*64+r]); return; } j -= 4096;
    if (j < 2560)  { ((u16*)(ws+O_WFCB))[j] = f2bf(wfc[j]); return; }
}

// ---- CSR build ----
__global__ __launch_bounds__(256) void zeroi_kernel(int* __restrict__ p, int n) {
    int i = blockIdx.x * 256 + threadIdx.x;
    if (i < n) p[i] = 0;
}
__global__ __launch_bounds__(256) void deg_count_kernel(const int* __restrict__ ei,
                                                        int* __restrict__ degi) {
    int e = blockIdx.x * 256 + threadIdx.x;
    if (e < NEDGE) atomicAdd(&degi[ei[NEDGE + e]], 1);
}
__global__ __launch_bounds__(256) void deg_inv_kernel(const int* __restrict__ degi,
                                                      float* __restrict__ dinv) {
    int i = blockIdx.x * 256 + threadIdx.x;
    if (i < NNODE) dinv[i] = rsqrtf(1.0f + (float)degi[i]);  // +1 self loop
}
// hierarchical scan: 196-block partials -> 1-block scan -> 196-block apply
__global__ __launch_bounds__(256) void psum_kernel(const int* __restrict__ degi,
                                                   int* __restrict__ psum) {
    int i = blockIdx.x * 256 + threadIdx.x;
    int v = (i < NNODE) ? degi[i] : 0;
    #pragma unroll
    for (int o = 32; o > 0; o >>= 1) v += __shfl_xor(v, o);
    __shared__ int s[4];
    int lane = threadIdx.x & 63, w = threadIdx.x >> 6;
    if (lane == 0) s[w] = v;
    __syncthreads();
    if (threadIdx.x == 0) psum[blockIdx.x] = s[0] + s[1] + s[2] + s[3];
}
__global__ __launch_bounds__(256) void scan_psum_kernel(int* __restrict__ psum, int nb) {
    int t = threadIdx.x;
    int v = (t < nb) ? psum[t] : 0;
    int lane = t & 63, w = t >> 6;
    int x = v;
    #pragma unroll
    for (int o = 1; o < 64; o <<= 1) { int u = __shfl_up(x, o); if (lane >= o) x += u; }
    __shared__ int ws4[4];
    if (lane == 63) ws4[w] = x;
    __syncthreads();
    int woff = 0;
    for (int i = 0; i < w; ++i) woff += ws4[i];
    psum[t] = woff + x - v;   // exclusive
}
__global__ __launch_bounds__(256) void scan_apply_kernel(const int* __restrict__ degi,
                                                         const int* __restrict__ psum,
                                                         int* __restrict__ rowptr,
                                                         int* __restrict__ cursor) {
    int i = blockIdx.x * 256 + threadIdx.x;
    int v = (i < NNODE) ? degi[i] : 0;
    int lane = threadIdx.x & 63, w = threadIdx.x >> 6;
    int x = v;
    #pragma unroll
    for (int o = 1; o < 64; o <<= 1) { int u = __shfl_up(x, o); if (lane >= o) x += u; }
    __shared__ int ws4[4];
    if (lane == 63) ws4[w] = x;
    __syncthreads();
    int woff = 0;
    for (int k = 0; k < w; ++k) woff += ws4[k];
    int run = psum[blockIdx.x] + woff + x - v;
    if (i < NNODE) { rowptr[i] = run; cursor[i] = run; }
    if (i == NNODE - 1) rowptr[NNODE] = run + v;
}
__global__ __launch_bounds__(256) void fill_kernel(const int* __restrict__ ei,
                                                   const float* __restrict__ dinv,
                                                   int* __restrict__ cursor,
                                                   int* __restrict__ col,
                                                   float* __restrict__ wcsr) {
    int e = blockIdx.x * 256 + threadIdx.x;
    if (e >= NEDGE) return;
    int s = ei[e], d = ei[NEDGE + e];
    int pos = atomicAdd(&cursor[d], 1);
    col[pos]  = s;
    wcsr[pos] = dinv[s] * dinv[d];
}

// ---- MFMA GEMM: C[M,Nn] = epi(A[M,K]bf16 @ Bt[Nn,K]bf16^T) ----
// Block=256 (4 waves), each wave: 16 rows x Nn cols. K = KS*32.
// Frag layouts (verified m89/m91/m92): A/B operand: lane&15 = m/n,
// elems = 8 contiguous k at (lane>>4)*8.  D: col=lane&15, row=(lane>>4)*4+reg.
// LOADACT: leaky_relu applied to A on load. EPI: 0 none(+bias), 1 leaky(+bias),
// 2: h + EPS*tanh(acc + agg + bias).
template<int KS, int NT, int LOADACT, int EPI>
__global__ __launch_bounds__(256) void mgemm(
    const u16* __restrict__ A,
    const u16* __restrict__ Bt,
    const float* __restrict__ bias,
    const float* __restrict__ agg,
    const float* __restrict__ hprev,
    float* __restrict__ outF,
    u16* __restrict__ outB,
    int M, int Nn, int ldc)
{
    const int wave = threadIdx.x >> 6;
    const int lane = threadIdx.x & 63;
    const int m = lane & 15, q = lane >> 4;
    const int rowbase = blockIdx.x * 64 + wave * 16;
    const int row = rowbase + m;
    const bool rok = row < M;
    const short8 z8 = {0,0,0,0,0,0,0,0};

    // register-cache all A fragments for this wave's 16 rows
    short8 af[KS];
    const short8* ap = (const short8*)(A + (long long)row * (KS * 32));
    #pragma unroll
    for (int k = 0; k < KS; ++k) af[k] = rok ? ap[k * 4 + q] : z8;
    if (LOADACT) {
        #pragma unroll
        for (int k = 0; k < KS; ++k)
            #pragma unroll
            for (int e = 0; e < 8; ++e) {
                float f = bf2f((u16)af[k][e]);
                f = f > 0.f ? f : 0.01f * f;
                af[k][e] = (short)f2bf(f);
            }
    }

    #pragma unroll
    for (int j = 0; j < NT; ++j) {
        const int coln = j * 16 + m;      // B row (output col) for operand load
        const bool cok = coln < Nn;
        const short8* bp = (const short8*)(Bt + (long long)coln * (KS * 32));
        f32x4 acc = {0.f, 0.f, 0.f, 0.f};
        #pragma unroll
        for (int k = 0; k < KS; ++k) {
            short8 bf_ = cok ? bp[k * 4 + q] : z8;
            acc = __builtin_amdgcn_mfma_f32_16x16x32_bf16(af[k], bf_, acc, 0, 0, 0);
        }
        // epilogue for this 16x16 tile: D col=lane&15 (== coln), row=q*4+r
        if (cok) {
            #pragma unroll
            for (int r = 0; r < 4; ++r) {
                int rowD = rowbase + q * 4 + r;
                if (rowD >= M) continue;
                long long o = (long long)rowD * ldc + coln;
                float v = acc[r];
                if (EPI == 2) {
                    v = hprev[o] + EPSC * tanhf(v + agg[o] + bias[coln]);
                } else {
                    if (bias) v += bias[coln];
                    if (EPI == 1) v = v > 0.f ? v : 0.01f * v;
                }
                if (outF) outF[o] = v;
                if (outB) outB[o] = f2bf(v);
            }
        }
    }
}

// ---- CSR gather: one wave per node, no atomics, includes self loop ----
template<int HD>
__global__ __launch_bounds__(256) void gather_kernel(
    const int* __restrict__ rowptr, const int* __restrict__ col,
    const float* __restrict__ wcsr, const float* __restrict__ dinv,
    const float* __restrict__ g, float* __restrict__ agg)
{
    int wave = (blockIdx.x * 256 + threadIdx.x) >> 6;
    int lane = threadIdx.x & 63;
    if (wave >= NNODE) return;
    const int n = wave;
    const int r0 = rowptr[n], r1 = rowptr[n + 1];
    const float wself = dinv[n] * dinv[n];

    float acc0, acc1 = 0.f;
    if (HD == 128) {
        float2 gs = *(const float2*)&g[(long long)n * 128 + lane * 2];
        acc0 = gs.x * wself; acc1 = gs.y * wself;
    } else {
        acc0 = g[(long long)n * 64 + lane] * wself;
    }

    for (int base = r0; base < r1; base += 64) {
        int idx = base + lane;
        int cs = 0; float cw = 0.f;
        if (idx < r1) { cs = col[idx]; cw = wcsr[idx]; }
        int cnt = min(64, r1 - base);
        for (int j = 0; j < cnt; ++j) {
            int   s = __shfl(cs, j);
            float w = __shfl(cw, j);
            if (HD == 128) {
                float2 gv = *(const float2*)&g[(long long)s * 128 + lane * 2];
                acc0 += gv.x * w; acc1 += gv.y * w;
            } else {
                acc0 += g[(long long)s * 64 + lane] * w;
            }
        }
    }

    if (HD == 128) {
        float2 o; o.x = acc0; o.y = acc1;
        *(float2*)&agg[(long long)n * 128 + lane * 2] = o;
    } else {
        agg[(long long)n * 64 + lane] = acc0;
    }
}

// ---- log_softmax over 40 classes, one wave per row, fp32 out ----
__global__ __launch_bounds__(256) void lsm_kernel(const float* __restrict__ z,
                                                  float* __restrict__ out)
{
    int gid = blockIdx.x * 256 + threadIdx.x;
    int row = gid >> 6;
    int lane = gid & 63;
    if (row >= NNODE) return;
    float v = (lane < 40) ? z[row * 40 + lane] : -1e30f;
    float m = v;
    #pragma unroll
    for (int o = 32; o > 0; o >>= 1) m = fmaxf(m, __shfl_xor(m, o));
    float e = (lane < 40) ? expf(v - m) : 0.f;
    float s = e;
    #pragma unroll
    for (int o = 32; o > 0; o >>= 1) s += __shfl_xor(s, o);
    float l = logf(s);
    if (lane < 40) out[row * 40 + lane] = v - m - l;
}

extern "C" void kernel_launch(void* const* d_in, const int* in_sizes, int n_in,
                              void* d_out, int out_size, void* d_ws, size_t ws_size,
                              hipStream_t stream) {
    const float* x     = (const float*)d_in[0];
    const int*   ei    = (const int*)d_in[1];
    const float* w_hid = (const float*)d_in[2];
    const float* b_hid = (const float*)d_in[3];
    const float* W_a1  = (const float*)d_in[4];
    const float* gcn1  = (const float*)d_in[5];
    const float* b_a1  = (const float*)d_in[6];
    const float* w2    = (const float*)d_in[7];
    const float* b2    = (const float*)d_in[8];
    const float* W_a2  = (const float*)d_in[9];
    const float* gcn2  = (const float*)d_in[10];
    const float* b_a2  = (const float*)d_in[11];
    const float* wfc   = (const float*)d_in[12];
    const float* bfc   = (const float*)d_in[13];
    float* ws = (float*)d_ws;
    float* out = (float*)d_out;

    float* dinv   = ws + O_DINV;
    int*   degi   = (int*)(ws + O_DEGI);
    int*   rowptr = (int*)(ws + O_ROWPTR);
    int*   cursor = (int*)(ws + O_CURSOR);
    int*   psum   = (int*)(ws + O_PSUM);
    int*   col    = (int*)(ws + O_COL);
    float* wcsr   = ws + O_WCSR;
    u16* whB  = (u16*)(ws + O_WHB);
    u16* g1tB = (u16*)(ws + O_G1TB);
    u16* aw1B = (u16*)(ws + O_AW1B);
    u16* w2B  = (u16*)(ws + O_W2B);
    u16* aw2B = (u16*)(ws + O_AW2B);
    u16* g2tB = (u16*)(ws + O_G2TB);
    u16* wfcB = (u16*)(ws + O_WFCB);
    float* hF0 = ws + O_HF0;
    float* hF1 = ws + O_HF1;
    float* agg = ws + O_AGG;
    float* gF  = ws + O_GF;
    u16* xb  = (u16*)(ws + O_GF);    // alias: xb dead before gF first written
    u16* hB0 = (u16*)(ws + O_HB0);
    u16* hB1 = (u16*)(ws + O_HB1);

    const int nScanB = (NNODE + 255) / 256;  // 196

    cvt_kernel<<<(NNODE * 256 / 4 + 255) / 256, 256, 0, stream>>>(x, xb, NNODE * 256 / 4);
    prep_kernel<<<(84480 + 255) / 256, 256, 0, stream>>>(w_hid, W_a1, gcn1, w2, W_a2, gcn2, wfc, ws);
    zeroi_kernel<<<nScanB, 256, 0, stream>>>(degi, NNODE);
    deg_count_kernel<<<(NEDGE + 255) / 256, 256, 0, stream>>>(ei, degi);
    deg_inv_kernel<<<nScanB, 256, 0, stream>>>(degi, dinv);
    psum_kernel<<<nScanB, 256, 0, stream>>>(degi, psum);
    scan_psum_kernel<<<1, 256, 0, stream>>>(psum, nScanB);
    scan_apply_kernel<<<nScanB, 256, 0, stream>>>(degi, psum, rowptr, cursor);
    fill_kernel<<<(NEDGE + 255) / 256, 256, 0, stream>>>(ei, dinv, cursor, col, wcsr);

    const int gB = (NNODE + 63) / 64;       // 782 row-blocks
    const int gatherBlocks = (NNODE * 64 + 255) / 256;

    // h = leaky_relu(x @ w_hid^T + b_hid) -> hF0 + hB0
    mgemm<8, 8, 0, 1><<<gB, 256, 0, stream>>>(
        xb, whB, b_hid, nullptr, nullptr, hF0, hB0, NNODE, 128, 128);

    // conv1: 3 iterations
    float* hFc = hF0; float* hFo = hF1;
    u16*   hBc = hB0; u16*   hBo = hB1;
    for (int it = 0; it < 3; ++it) {
        mgemm<4, 8, 0, 0><<<gB, 256, 0, stream>>>(
            hBc, g1tB, nullptr, nullptr, nullptr, gF, nullptr, NNODE, 128, 128);
        gather_kernel<128><<<gatherBlocks, 256, 0, stream>>>(
            rowptr, col, wcsr, dinv, gF, agg);
        mgemm<4, 8, 0, 2><<<gB, 256, 0, stream>>>(
            hBc, aw1B, b_a1, agg, hFc, hFo, hBo, NNODE, 128, 128);
        float* tf = hFc; hFc = hFo; hFo = tf;
        u16*   tb = hBc; hBc = hBo; hBo = tb;
    }

    // h2 = leaky_relu(leaky_relu(h) @ w2^T + b2) -> hFo(first half) + hBo
    mgemm<4, 4, 1, 1><<<gB, 256, 0, stream>>>(
        hBc, w2B, b2, nullptr, nullptr, hFo, hBo, NNODE, 64, 64);
    float* h2F = hFo; u16* h2B = hBo;
    float* spF = hFc; u16* spB = hBc;   // dead, reusable

    // conv2: 1 iteration
    mgemm<2, 4, 0, 0><<<gB, 256, 0, stream>>>(
        h2B, g2tB, nullptr, nullptr, nullptr, gF, nullptr, NNODE, 64, 64);
    gather_kernel<64><<<gatherBlocks, 256, 0, stream>>>(
        rowptr, col, wcsr, dinv, gF, agg);
    mgemm<2, 4, 0, 2><<<gB, 256, 0, stream>>>(
        h2B, aw2B, b_a2, agg, h2F, spF, spB, NNODE, 64, 64);

    // z = h2n @ w_fc^T + b_fc -> gF (ldc=40)
    mgemm<2, 3, 0, 0><<<gB, 256, 0, stream>>>(
        spB, wfcB, bfc, nullptr, nullptr, gF, nullptr, NNODE, 40, 40);

    lsm_kernel<<<(NNODE * 64 + 255) / 256, 256, 0, stream>>>(gF, out);
}

// Round 8
// 560.549 us; speedup vs baseline: 3.2605x; 1.2103x over previous
//
#include <hip/hip_runtime.h>
#include <hip/hip_bf16.h>
#include <math.h>

typedef unsigned short u16;
using short8 = __attribute__((ext_vector_type(8))) short;
using f32x4  = __attribute__((ext_vector_type(4))) float;

static constexpr int NNODE = 50000;
static constexpr int NEDGE = 600000;
static constexpr float EPSC   = 0.1f;
static constexpr float GAMMAC = 0.1f;

// ---- workspace layout (float-index offsets) ----
static constexpr long long O_DINV   = 0;                         // float 50000
static constexpr long long O_DEGI   = 50000;                     // int 50000
static constexpr long long O_ROWPTR = 100000;                    // int 50001
static constexpr long long O_CURSOR = 150004;                    // int 50000
static constexpr long long O_PSUM   = 200004;                    // int 256
static constexpr long long O_COL    = 200260;                    // int 600000
static constexpr long long O_WCSR   = 800260;                    // float 600000
// bf16 weights (float slots = bf16count/2)
static constexpr long long O_WHB    = 1400260;                   // 32768 bf16
static constexpr long long O_G1TB   = O_WHB  + 16384;            // 16384 bf16
static constexpr long long O_AW1B   = O_G1TB + 8192;             // 16384 bf16
static constexpr long long O_W2B    = O_AW1B + 8192;             // 8192 bf16
static constexpr long long O_AW2B   = O_W2B  + 4096;             // 4096 bf16
static constexpr long long O_G2TB   = O_AW2B + 2048;             // 4096 bf16
static constexpr long long O_WFCB   = O_G2TB + 2048;             // 2560 bf16
// big buffers (bf16 activations; fp32 only for final z)
static constexpr long long O_Z      = 1450000;                   // float 2.0M
static constexpr long long O_GB     = 3450004;                   // bf16 6.4M (3.2M fl)
static constexpr long long O_AGGB   = O_GB   + 3200000;          // bf16 6.4M
static constexpr long long O_HB0    = O_AGGB + 3200000;          // bf16 6.4M
static constexpr long long O_HB1    = O_HB0  + 3200000;          // bf16 6.4M

__device__ __forceinline__ float bf2f(u16 u) {
    return __uint_as_float(((unsigned)u) << 16);
}
__device__ __forceinline__ u16 f2bf(float f) {
    unsigned u = __float_as_uint(f);
    return (u16)((u + 0x7FFFu + ((u >> 16) & 1u)) >> 16);
}

// ---- weight prep: antisymmetrize / transpose, all to bf16 ----
__global__ __launch_bounds__(256) void prep_kernel(
    const float* __restrict__ w_hid, const float* __restrict__ W_a1,
    const float* __restrict__ gcn1,  const float* __restrict__ w2,
    const float* __restrict__ W_a2,  const float* __restrict__ gcn2,
    const float* __restrict__ wfc,   float* __restrict__ ws)
{
    int j = blockIdx.x * 256 + threadIdx.x;
    if (j < 32768) { ((u16*)(ws+O_WHB))[j] = f2bf(w_hid[j]); return; } j -= 32768;
    if (j < 16384) { int r=j>>7, c=j&127; ((u16*)(ws+O_G1TB))[j] = f2bf(gcn1[c*128+r]); return; } j -= 16384;
    if (j < 16384) { int r=j>>7, c=j&127;
                     ((u16*)(ws+O_AW1B))[j] = f2bf(W_a1[r*128+c] - W_a1[c*128+r] - (r==c?GAMMAC:0.f));
                     return; } j -= 16384;
    if (j < 8192)  { ((u16*)(ws+O_W2B))[j] = f2bf(w2[j]); return; } j -= 8192;
    if (j < 4096)  { int r=j>>6, c=j&63;
                     ((u16*)(ws+O_AW2B))[j] = f2bf(W_a2[r*64+c] - W_a2[c*64+r] - (r==c?GAMMAC:0.f));
                     return; } j -= 4096;
    if (j < 4096)  { int r=j>>6, c=j&63; ((u16*)(ws+O_G2TB))[j] = f2bf(gcn2[c*64+r]); return; } j -= 4096;
    if (j < 2560)  { ((u16*)(ws+O_WFCB))[j] = f2bf(wfc[j]); return; }
}

// ---- CSR build ----
__global__ __launch_bounds__(256) void zeroi_kernel(int* __restrict__ p, int n) {
    int i = blockIdx.x * 256 + threadIdx.x;
    if (i < n) p[i] = 0;
}
__global__ __launch_bounds__(256) void deg_count_kernel(const int* __restrict__ ei,
                                                        int* __restrict__ degi) {
    int e = blockIdx.x * 256 + threadIdx.x;
    if (e < NEDGE) atomicAdd(&degi[ei[NEDGE + e]], 1);
}
__global__ __launch_bounds__(256) void deg_inv_kernel(const int* __restrict__ degi,
                                                      float* __restrict__ dinv) {
    int i = blockIdx.x * 256 + threadIdx.x;
    if (i < NNODE) dinv[i] = rsqrtf(1.0f + (float)degi[i]);  // +1 self loop
}
// hierarchical scan: 196-block partials -> 1-block scan -> 196-block apply
__global__ __launch_bounds__(256) void psum_kernel(const int* __restrict__ degi,
                                                   int* __restrict__ psum) {
    int i = blockIdx.x * 256 + threadIdx.x;
    int v = (i < NNODE) ? degi[i] : 0;
    #pragma unroll
    for (int o = 32; o > 0; o >>= 1) v += __shfl_xor(v, o);
    __shared__ int s[4];
    int lane = threadIdx.x & 63, w = threadIdx.x >> 6;
    if (lane == 0) s[w] = v;
    __syncthreads();
    if (threadIdx.x == 0) psum[blockIdx.x] = s[0] + s[1] + s[2] + s[3];
}
__global__ __launch_bounds__(256) void scan_psum_kernel(int* __restrict__ psum, int nb) {
    int t = threadIdx.x;
    int v = (t < nb) ? psum[t] : 0;
    int lane = t & 63, w = t >> 6;
    int x = v;
    #pragma unroll
    for (int o = 1; o < 64; o <<= 1) { int u = __shfl_up(x, o); if (lane >= o) x += u; }
    __shared__ int ws4[4];
    if (lane == 63) ws4[w] = x;
    __syncthreads();
    int woff = 0;
    for (int i = 0; i < w; ++i) woff += ws4[i];
    psum[t] = woff + x - v;   // exclusive
}
__global__ __launch_bounds__(256) void scan_apply_kernel(const int* __restrict__ degi,
                                                         const int* __restrict__ psum,
                                                         int* __restrict__ rowptr,
                                                         int* __restrict__ cursor) {
    int i = blockIdx.x * 256 + threadIdx.x;
    int v = (i < NNODE) ? degi[i] : 0;
    int lane = threadIdx.x & 63, w = threadIdx.x >> 6;
    int x = v;
    #pragma unroll
    for (int o = 1; o < 64; o <<= 1) { int u = __shfl_up(x, o); if (lane >= o) x += u; }
    __shared__ int ws4[4];
    if (lane == 63) ws4[w] = x;
    __syncthreads();
    int woff = 0;
    for (int k = 0; k < w; ++k) woff += ws4[k];
    int run = psum[blockIdx.x] + woff + x - v;
    if (i < NNODE) { rowptr[i] = run; cursor[i] = run; }
    if (i == NNODE - 1) rowptr[NNODE] = run + v;
}
__global__ __launch_bounds__(256) void fill_kernel(const int* __restrict__ ei,
                                                   const float* __restrict__ dinv,
                                                   int* __restrict__ cursor,
                                                   int* __restrict__ col,
                                                   float* __restrict__ wcsr) {
    int e = blockIdx.x * 256 + threadIdx.x;
    if (e >= NEDGE) return;
    int s = ei[e], d = ei[NEDGE + e];
    int pos = atomicAdd(&cursor[d], 1);
    col[pos]  = s;
    wcsr[pos] = dinv[s] * dinv[d];
}

// ---- MFMA GEMM: C[M,Nn] = epi(A[M,K] @ Bt[Nn,K]^T) ----
// A is bf16 (or fp32 when AF32=1, converted on load). 4 waves x 16 rows.
// EPI: 0 none(+bias)->outF/outB, 1 leaky(+bias)->outB,
//      2: h + EPS*tanh(acc + agg + bias) with h,agg bf16 ->outB.
template<int KS, int NT, int AF32, int LOADACT, int EPI>
__global__ __launch_bounds__(256) void mgemm(
    const void* __restrict__ Araw,
    const u16* __restrict__ Bt,
    const float* __restrict__ bias,
    const u16* __restrict__ aggB,
    const u16* __restrict__ hprevB,
    float* __restrict__ outF,
    u16* __restrict__ outB,
    int M, int Nn, int ldc)
{
    const int wave = threadIdx.x >> 6;
    const int lane = threadIdx.x & 63;
    const int m = lane & 15, q = lane >> 4;
    const int rowbase = blockIdx.x * 64 + wave * 16;
    const int row = rowbase + m;
    const bool rok = row < M;
    const short8 z8 = {0,0,0,0,0,0,0,0};

    // register-cache all A fragments for this wave's 16 rows
    short8 af[KS];
    if (AF32) {
        const float* apf = (const float*)Araw + (long long)row * (KS * 32);
        #pragma unroll
        for (int k = 0; k < KS; ++k) {
            short8 t = z8;
            if (rok) {
                const float4* p = (const float4*)(apf + (k * 4 + q) * 8);
                float4 a = p[0], b = p[1];
                t[0]=(short)f2bf(a.x); t[1]=(short)f2bf(a.y); t[2]=(short)f2bf(a.z); t[3]=(short)f2bf(a.w);
                t[4]=(short)f2bf(b.x); t[5]=(short)f2bf(b.y); t[6]=(short)f2bf(b.z); t[7]=(short)f2bf(b.w);
            }
            af[k] = t;
        }
    } else {
        const short8* ap = (const short8*)((const u16*)Araw + (long long)row * (KS * 32));
        #pragma unroll
        for (int k = 0; k < KS; ++k) af[k] = rok ? ap[k * 4 + q] : z8;
    }
    if (LOADACT) {
        #pragma unroll
        for (int k = 0; k < KS; ++k)
            #pragma unroll
            for (int e = 0; e < 8; ++e) {
                float f = bf2f((u16)af[k][e]);
                f = f > 0.f ? f : 0.01f * f;
                af[k][e] = (short)f2bf(f);
            }
    }

    #pragma unroll
    for (int j = 0; j < NT; ++j) {
        const int coln = j * 16 + m;      // B row (output col) for operand load
        const bool cok = coln < Nn;
        const short8* bp = (const short8*)(Bt + (long long)coln * (KS * 32));
        f32x4 acc = {0.f, 0.f, 0.f, 0.f};
        #pragma unroll
        for (int k = 0; k < KS; ++k) {
            short8 bf_ = cok ? bp[k * 4 + q] : z8;
            acc = __builtin_amdgcn_mfma_f32_16x16x32_bf16(af[k], bf_, acc, 0, 0, 0);
        }
        // epilogue: D col=lane&15 (== coln), row=q*4+r
        if (cok) {
            #pragma unroll
            for (int r = 0; r < 4; ++r) {
                int rowD = rowbase + q * 4 + r;
                if (rowD >= M) continue;
                long long o = (long long)rowD * ldc + coln;
                float v = acc[r];
                if (EPI == 2) {
                    v = bf2f(hprevB[o]) + EPSC * tanhf(v + bf2f(aggB[o]) + bias[coln]);
                } else {
                    if (bias) v += bias[coln];
                    if (EPI == 1) v = v > 0.f ? v : 0.01f * v;
                }
                if (outF) outF[o] = v;
                if (outB) outB[o] = f2bf(v);
            }
        }
    }
}

// ---- CSR gather (bf16 in/out): one wave per node, two 32-lane halves each
// process one neighbor per iteration; xor-reduce at the end. Self loop incl.
template<int HD>
__global__ __launch_bounds__(256) void gather_kernel(
    const int* __restrict__ rowptr, const int* __restrict__ col,
    const float* __restrict__ wcsr, const float* __restrict__ dinv,
    const u16* __restrict__ gB, u16* __restrict__ aggB)
{
    int node = (blockIdx.x * 256 + threadIdx.x) >> 6;
    int lane = threadIdx.x & 63;
    if (node >= NNODE) return;
    const int half = lane >> 5, l5 = lane & 31;
    const int r0 = rowptr[node], r1 = rowptr[node + 1];
    const float wself = dinv[node] * dinv[node];

    float a0 = 0.f, a1 = 0.f, a2 = 0.f, a3 = 0.f;
    if (half == 0) {
        if (HD == 128) {
            ushort4 gs = *(const ushort4*)&gB[(long long)node * 128 + l5 * 4];
            a0 = bf2f(gs.x) * wself; a1 = bf2f(gs.y) * wself;
            a2 = bf2f(gs.z) * wself; a3 = bf2f(gs.w) * wself;
        } else {
            ushort2 gs = *(const ushort2*)&gB[(long long)node * 64 + l5 * 2];
            a0 = bf2f(gs.x) * wself; a1 = bf2f(gs.y) * wself;
        }
    }

    for (int base = r0; base < r1; base += 64) {
        int idx = base + lane;
        int cs = 0; float cw = 0.f;
        if (idx < r1) { cs = col[idx]; cw = wcsr[idx]; }
        int cnt = min(64, r1 - base);
        for (int j = 0; j < cnt; j += 2) {
            int jj = j + half;                 // <= 63 always (cnt<=64)
            int   s = __shfl(cs, jj);          // cs=0,cw=0 beyond cnt -> harmless
            float w = __shfl(cw, jj);
            if (HD == 128) {
                ushort4 gv = *(const ushort4*)&gB[(long long)s * 128 + l5 * 4];
                a0 += bf2f(gv.x) * w; a1 += bf2f(gv.y) * w;
                a2 += bf2f(gv.z) * w; a3 += bf2f(gv.w) * w;
            } else {
                ushort2 gv = *(const ushort2*)&gB[(long long)s * 64 + l5 * 2];
                a0 += bf2f(gv.x) * w; a1 += bf2f(gv.y) * w;
            }
        }
    }

    a0 += __shfl_xor(a0, 32); a1 += __shfl_xor(a1, 32);
    if (HD == 128) { a2 += __shfl_xor(a2, 32); a3 += __shfl_xor(a3, 32); }

    if (half == 0) {
        if (HD == 128) {
            ushort4 o;
            o.x = f2bf(a0); o.y = f2bf(a1); o.z = f2bf(a2); o.w = f2bf(a3);
            *(ushort4*)&aggB[(long long)node * 128 + l5 * 4] = o;
        } else {
            ushort2 o;
            o.x = f2bf(a0); o.y = f2bf(a1);
            *(ushort2*)&aggB[(long long)node * 64 + l5 * 2] = o;
        }
    }
}

// ---- log_softmax over 40 classes, one wave per row, fp32 out ----
__global__ __launch_bounds__(256) void lsm_kernel(const float* __restrict__ z,
                                                  float* __restrict__ out)
{
    int gid = blockIdx.x * 256 + threadIdx.x;
    int row = gid >> 6;
    int lane = gid & 63;
    if (row >= NNODE) return;
    float v = (lane < 40) ? z[row * 40 + lane] : -1e30f;
    float m = v;
    #pragma unroll
    for (int o = 32; o > 0; o >>= 1) m = fmaxf(m, __shfl_xor(m, o));
    float e = (lane < 40) ? expf(v - m) : 0.f;
    float s = e;
    #pragma unroll
    for (int o = 32; o > 0; o >>= 1) s += __shfl_xor(s, o);
    float l = logf(s);
    if (lane < 40) out[row * 40 + lane] = v - m - l;
}

extern "C" void kernel_launch(void* const* d_in, const int* in_sizes, int n_in,
                              void* d_out, int out_size, void* d_ws, size_t ws_size,
                              hipStream_t stream) {
    const float* x     = (const float*)d_in[0];
    const int*   ei    = (const int*)d_in[1];
    const float* w_hid = (const float*)d_in[2];
    const float* b_hid = (const float*)d_in[3];
    const float* W_a1  = (const float*)d_in[4];
    const float* gcn1  = (const float*)d_in[5];
    const float* b_a1  = (const float*)d_in[6];
    const float* w2    = (const float*)d_in[7];
    const float* b2    = (const float*)d_in[8];
    const float* W_a2  = (const float*)d_in[9];
    const float* gcn2  = (const float*)d_in[10];
    const float* b_a2  = (const float*)d_in[11];
    const float* wfc   = (const float*)d_in[12];
    const float* bfc   = (const float*)d_in[13];
    float* ws = (float*)d_ws;
    float* out = (float*)d_out;

    float* dinv   = ws + O_DINV;
    int*   degi   = (int*)(ws + O_DEGI);
    int*   rowptr = (int*)(ws + O_ROWPTR);
    int*   cursor = (int*)(ws + O_CURSOR);
    int*   psum   = (int*)(ws + O_PSUM);
    int*   col    = (int*)(ws + O_COL);
    float* wcsr   = ws + O_WCSR;
    u16* whB  = (u16*)(ws + O_WHB);
    u16* g1tB = (u16*)(ws + O_G1TB);
    u16* aw1B = (u16*)(ws + O_AW1B);
    u16* w2B  = (u16*)(ws + O_W2B);
    u16* aw2B = (u16*)(ws + O_AW2B);
    u16* g2tB = (u16*)(ws + O_G2TB);
    u16* wfcB = (u16*)(ws + O_WFCB);
    float* zF  = ws + O_Z;
    u16* gBuf = (u16*)(ws + O_GB);
    u16* aggB = (u16*)(ws + O_AGGB);
    u16* hB0  = (u16*)(ws + O_HB0);
    u16* hB1  = (u16*)(ws + O_HB1);

    const int nScanB = (NNODE + 255) / 256;  // 196

    prep_kernel<<<(84480 + 255) / 256, 256, 0, stream>>>(w_hid, W_a1, gcn1, w2, W_a2, gcn2, wfc, ws);
    zeroi_kernel<<<nScanB, 256, 0, stream>>>(degi, NNODE);
    deg_count_kernel<<<(NEDGE + 255) / 256, 256, 0, stream>>>(ei, degi);
    deg_inv_kernel<<<nScanB, 256, 0, stream>>>(degi, dinv);
    psum_kernel<<<nScanB, 256, 0, stream>>>(degi, psum);
    scan_psum_kernel<<<1, 256, 0, stream>>>(psum, nScanB);
    scan_apply_kernel<<<nScanB, 256, 0, stream>>>(degi, psum, rowptr, cursor);
    fill_kernel<<<(NEDGE + 255) / 256, 256, 0, stream>>>(ei, dinv, cursor, col, wcsr);

    const int gB = (NNODE + 63) / 64;       // 782 row-blocks
    const int gatherBlocks = (NNODE * 64 + 255) / 256;

    // h = leaky_relu(x @ w_hid^T + b_hid) -> hB0 (fp32 A converted on load)
    mgemm<8, 8, 1, 0, 1><<<gB, 256, 0, stream>>>(
        x, whB, b_hid, nullptr, nullptr, nullptr, hB0, NNODE, 128, 128);

    // conv1: 3 iterations (all-bf16 residual pipeline)
    u16* hBc = hB0; u16* hBo = hB1;
    for (int it = 0; it < 3; ++it) {
        mgemm<4, 8, 0, 0, 0><<<gB, 256, 0, stream>>>(
            hBc, g1tB, nullptr, nullptr, nullptr, nullptr, gBuf, NNODE, 128, 128);
        gather_kernel<128><<<gatherBlocks, 256, 0, stream>>>(
            rowptr, col, wcsr, dinv, gBuf, aggB);
        mgemm<4, 8, 0, 0, 2><<<gB, 256, 0, stream>>>(
            hBc, aw1B, b_a1, aggB, hBc, nullptr, hBo, NNODE, 128, 128);
        u16* tb = hBc; hBc = hBo; hBo = tb;
    }

    // h2 = leaky_relu(leaky_relu(h) @ w2^T + b2) -> hBo
    mgemm<4, 4, 0, 1, 1><<<gB, 256, 0, stream>>>(
        hBc, w2B, b2, nullptr, nullptr, nullptr, hBo, NNODE, 64, 64);
    u16* h2B = hBo;
    u16* spB = hBc;   // dead, reusable

    // conv2: 1 iteration
    mgemm<2, 4, 0, 0, 0><<<gB, 256, 0, stream>>>(
        h2B, g2tB, nullptr, nullptr, nullptr, nullptr, gBuf, NNODE, 64, 64);
    gather_kernel<64><<<gatherBlocks, 256, 0, stream>>>(
        rowptr, col, wcsr, dinv, gBuf, aggB);
    mgemm<2, 4, 0, 0, 2><<<gB, 256, 0, stream>>>(
        h2B, aw2B, b_a2, aggB, h2B, nullptr, spB, NNODE, 64, 64);

    // z = h2n @ w_fc^T + b_fc -> zF (fp32)
    mgemm<2, 3, 0, 0, 0><<<gB, 256, 0, stream>>>(
        spB, wfcB, bfc, nullptr, nullptr, zF, nullptr, NNODE, 40, 40);

    lsm_kernel<<<(NNODE * 64 + 255) / 256, 256, 0, stream>>>(zF, out);
}

// Round 9
// 495.577 us; speedup vs baseline: 3.6880x; 1.1311x over previous
//
#include <hip/hip_runtime.h>
#include <hip/hip_bf16.h>
#include <math.h>

typedef unsigned short u16;
using short8 = __attribute__((ext_vector_type(8))) short;
using f32x4  = __attribute__((ext_vector_type(4))) float;

static constexpr int NNODE = 50000;
static constexpr int NEDGE = 600000;
static constexpr float EPSC   = 0.1f;
static constexpr float GAMMAC = 0.1f;

// ---- workspace layout (float-index offsets) ----
static constexpr long long O_DINV   = 0;                         // float 50000
static constexpr long long O_DEGI   = 50000;                     // int 50000
static constexpr long long O_ROWPTR = 100000;                    // int 50001
static constexpr long long O_CURSOR = 150004;                    // int 50000
static constexpr long long O_PSUM   = 200004;                    // int 256
static constexpr long long O_COL    = 200260;                    // int 600000
static constexpr long long O_WCSR   = 800260;                    // float 600000
// bf16 weights (float slots = bf16count/2)
static constexpr long long O_WHB    = 1400260;                   // 32768 bf16
static constexpr long long O_G1TB   = O_WHB  + 16384;            // 16384 bf16
static constexpr long long O_AW1B   = O_G1TB + 8192;             // 16384 bf16
static constexpr long long O_W2B    = O_AW1B + 8192;             // 8192 bf16
static constexpr long long O_AW2B   = O_W2B  + 4096;             // 4096 bf16
static constexpr long long O_G2TB   = O_AW2B + 2048;             // 4096 bf16
static constexpr long long O_WFCB   = O_G2TB + 2048;             // 2560 bf16
// big buffers (bf16 activations; fp32 only for final z)
static constexpr long long O_Z      = 1450000;                   // float 2.0M
static constexpr long long O_GB     = 3450004;                   // bf16 6.4M (3.2M fl)
static constexpr long long O_AGGB   = O_GB   + 3200000;          // bf16 6.4M
static constexpr long long O_HB0    = O_AGGB + 3200000;          // bf16 6.4M
static constexpr long long O_HB1    = O_HB0  + 3200000;          // bf16 6.4M

__device__ __forceinline__ float bf2f(u16 u) {
    return __uint_as_float(((unsigned)u) << 16);
}
__device__ __forceinline__ u16 f2bf(float f) {
    unsigned u = __float_as_uint(f);
    return (u16)((u + 0x7FFFu + ((u >> 16) & 1u)) >> 16);
}

// ---- weight prep: antisymmetrize / transpose, all to bf16 ----
__global__ __launch_bounds__(256) void prep_kernel(
    const float* __restrict__ w_hid, const float* __restrict__ W_a1,
    const float* __restrict__ gcn1,  const float* __restrict__ w2,
    const float* __restrict__ W_a2,  const float* __restrict__ gcn2,
    const float* __restrict__ wfc,   float* __restrict__ ws)
{
    int j = blockIdx.x * 256 + threadIdx.x;
    if (j < 32768) { ((u16*)(ws+O_WHB))[j] = f2bf(w_hid[j]); return; } j -= 32768;
    if (j < 16384) { int r=j>>7, c=j&127; ((u16*)(ws+O_G1TB))[j] = f2bf(gcn1[c*128+r]); return; } j -= 16384;
    if (j < 16384) { int r=j>>7, c=j&127;
                     ((u16*)(ws+O_AW1B))[j] = f2bf(W_a1[r*128+c] - W_a1[c*128+r] - (r==c?GAMMAC:0.f));
                     return; } j -= 16384;
    if (j < 8192)  { ((u16*)(ws+O_W2B))[j] = f2bf(w2[j]); return; } j -= 8192;
    if (j < 4096)  { int r=j>>6, c=j&63;
                     ((u16*)(ws+O_AW2B))[j] = f2bf(W_a2[r*64+c] - W_a2[c*64+r] - (r==c?GAMMAC:0.f));
                     return; } j -= 4096;
    if (j < 4096)  { int r=j>>6, c=j&63; ((u16*)(ws+O_G2TB))[j] = f2bf(gcn2[c*64+r]); return; } j -= 4096;
    if (j < 2560)  { ((u16*)(ws+O_WFCB))[j] = f2bf(wfc[j]); return; }
}

// ---- CSR build ----
__global__ __launch_bounds__(256) void zeroi_kernel(int* __restrict__ p, int n) {
    int i = blockIdx.x * 256 + threadIdx.x;
    if (i < n) p[i] = 0;
}
__global__ __launch_bounds__(256) void deg_count_kernel(const int* __restrict__ ei,
                                                        int* __restrict__ degi) {
    int e = blockIdx.x * 256 + threadIdx.x;
    if (e < NEDGE) atomicAdd(&degi[ei[NEDGE + e]], 1);
}
__global__ __launch_bounds__(256) void deg_inv_kernel(const int* __restrict__ degi,
                                                      float* __restrict__ dinv) {
    int i = blockIdx.x * 256 + threadIdx.x;
    if (i < NNODE) dinv[i] = rsqrtf(1.0f + (float)degi[i]);  // +1 self loop
}
// hierarchical scan: 196-block partials -> 1-block scan -> 196-block apply
__global__ __launch_bounds__(256) void psum_kernel(const int* __restrict__ degi,
                                                   int* __restrict__ psum) {
    int i = blockIdx.x * 256 + threadIdx.x;
    int v = (i < NNODE) ? degi[i] : 0;
    #pragma unroll
    for (int o = 32; o > 0; o >>= 1) v += __shfl_xor(v, o);
    __shared__ int s[4];
    int lane = threadIdx.x & 63, w = threadIdx.x >> 6;
    if (lane == 0) s[w] = v;
    __syncthreads();
    if (threadIdx.x == 0) psum[blockIdx.x] = s[0] + s[1] + s[2] + s[3];
}
__global__ __launch_bounds__(256) void scan_psum_kernel(int* __restrict__ psum, int nb) {
    int t = threadIdx.x;
    int v = (t < nb) ? psum[t] : 0;
    int lane = t & 63, w = t >> 6;
    int x = v;
    #pragma unroll
    for (int o = 1; o < 64; o <<= 1) { int u = __shfl_up(x, o); if (lane >= o) x += u; }
    __shared__ int ws4[4];
    if (lane == 63) ws4[w] = x;
    __syncthreads();
    int woff = 0;
    for (int i = 0; i < w; ++i) woff += ws4[i];
    psum[t] = woff + x - v;   // exclusive
}
__global__ __launch_bounds__(256) void scan_apply_kernel(const int* __restrict__ degi,
                                                         const int* __restrict__ psum,
                                                         int* __restrict__ rowptr,
                                                         int* __restrict__ cursor) {
    int i = blockIdx.x * 256 + threadIdx.x;
    int v = (i < NNODE) ? degi[i] : 0;
    int lane = threadIdx.x & 63, w = threadIdx.x >> 6;
    int x = v;
    #pragma unroll
    for (int o = 1; o < 64; o <<= 1) { int u = __shfl_up(x, o); if (lane >= o) x += u; }
    __shared__ int ws4[4];
    if (lane == 63) ws4[w] = x;
    __syncthreads();
    int woff = 0;
    for (int k = 0; k < w; ++k) woff += ws4[k];
    int run = psum[blockIdx.x] + woff + x - v;
    if (i < NNODE) { rowptr[i] = run; cursor[i] = run; }
    if (i == NNODE - 1) rowptr[NNODE] = run + v;
}
__global__ __launch_bounds__(256) void fill_kernel(const int* __restrict__ ei,
                                                   const float* __restrict__ dinv,
                                                   int* __restrict__ cursor,
                                                   int* __restrict__ col,
                                                   float* __restrict__ wcsr) {
    int e = blockIdx.x * 256 + threadIdx.x;
    if (e >= NEDGE) return;
    int s = ei[e], d = ei[NEDGE + e];
    int pos = atomicAdd(&cursor[d], 1);
    col[pos]  = s;
    wcsr[pos] = dinv[s] * dinv[d];
}

// ---- MFMA GEMM v2: LDS-staged B, LDS-transposed epilogue ----
// Block = 256 threads (4 waves), 64 rows/block, full Nn per wave.
// B (Nn x K bf16, row pitch K+8 in LDS) staged per 128-col chunk; after the
// MFMA loop the same LDS holds the fp32 acc for a coalesced epilogue.
// EPI: 0 none(+bias), 1 leaky(+bias), 2: h + EPS*tanh(acc + agg + bias).
template<int KS, int NT, int AF32, int LOADACT, int EPI>
__global__ __launch_bounds__(256, 4) void mgemm(
    const void* __restrict__ Araw,
    const u16* __restrict__ Bt,
    const float* __restrict__ bias,
    const u16* __restrict__ aggB,
    const u16* __restrict__ hprevB,
    float* __restrict__ outF,
    u16* __restrict__ outB,
    int M, int Nn, int ldc)
{
    constexpr int K    = KS * 32;
    constexpr int KCHU = (K > 128) ? 128 : K;   // B chunk width (u16 cols)
    constexpr int KC   = KCHU / 32;             // MFMA steps per chunk
    constexpr int NCH  = K / KCHU;              // chunks
    constexpr int P    = KCHU + 8;              // LDS row pitch (u16), 16B-aligned
    constexpr int ROWS = NT * 16;               // B rows staged
    constexpr int CW   = NT * 16 + 1;           // acc LDS row pitch (f32)
    constexpr int BSZ  = ROWS * P * 2;
    constexpr int ASZ  = 64 * CW * 4;
    constexpr int SMEM = BSZ > ASZ ? BSZ : ASZ;
    __shared__ __align__(16) char smem[SMEM];
    u16*   bl   = (u16*)smem;
    float* accL = (float*)smem;

    const int wave = threadIdx.x >> 6;
    const int lane = threadIdx.x & 63;
    const int m = lane & 15, q = lane >> 4;
    const int rowbase = blockIdx.x * 64 + wave * 16;
    const int row = rowbase + m;
    const bool rok = row < M;
    const short8 z8 = {0,0,0,0,0,0,0,0};

    // A fragments for this wave's 16 rows (issued before B staging for overlap)
    short8 af[KS];
    if (AF32) {
        const float* apf = (const float*)Araw + (long long)row * K;
        #pragma unroll
        for (int k = 0; k < KS; ++k) {
            short8 t = z8;
            if (rok) {
                const float4* p = (const float4*)(apf + (k * 4 + q) * 8);
                float4 a = p[0], b = p[1];
                t[0]=(short)f2bf(a.x); t[1]=(short)f2bf(a.y); t[2]=(short)f2bf(a.z); t[3]=(short)f2bf(a.w);
                t[4]=(short)f2bf(b.x); t[5]=(short)f2bf(b.y); t[6]=(short)f2bf(b.z); t[7]=(short)f2bf(b.w);
            }
            af[k] = t;
        }
    } else {
        const short8* ap = (const short8*)((const u16*)Araw + (long long)row * K);
        #pragma unroll
        for (int k = 0; k < KS; ++k) af[k] = rok ? ap[k * 4 + q] : z8;
    }
    if (LOADACT) {
        #pragma unroll
        for (int k = 0; k < KS; ++k)
            #pragma unroll
            for (int e = 0; e < 8; ++e) {
                float f = bf2f((u16)af[k][e]);
                f = f > 0.f ? f : 0.01f * f;
                af[k][e] = (short)f2bf(f);
            }
    }

    f32x4 acc[NT];
    #pragma unroll
    for (int j = 0; j < NT; ++j) acc[j] = (f32x4){0.f,0.f,0.f,0.f};

    for (int ch = 0; ch < NCH; ++ch) {
        if (ch) __syncthreads();
        // stage B chunk into LDS (zero rows >= Nn)
        constexpr int CHUNKS = ROWS * (KCHU / 8);
        for (int t = threadIdx.x; t < CHUNKS; t += 256) {
            int r = t / (KCHU / 8), c = t - r * (KCHU / 8);
            short8 v = z8;
            if (r < Nn) v = *(const short8*)&Bt[(long long)r * K + ch * KCHU + c * 8];
            *(short8*)&bl[r * P + c * 8] = v;
        }
        __syncthreads();
        #pragma unroll
        for (int j = 0; j < NT; ++j) {
            #pragma unroll
            for (int k = 0; k < KC; ++k) {
                short8 bf_ = *(const short8*)&bl[(j * 16 + m) * P + k * 32 + q * 8];
                acc[j] = __builtin_amdgcn_mfma_f32_16x16x32_bf16(af[ch * KC + k], bf_, acc[j], 0, 0, 0);
            }
        }
    }

    __syncthreads();            // all waves done reading B; reuse LDS for acc
    // D layout: col = j*16 + (lane&15), row = (lane>>4)*4 + r
    #pragma unroll
    for (int j = 0; j < NT; ++j)
        #pragma unroll
        for (int r = 0; r < 4; ++r)
            accL[(wave * 16 + q * 4 + r) * CW + j * 16 + m] = acc[j][r];
    __syncthreads();

    // coalesced epilogue: each lane owns 2 consecutive cols of its wave's rows
    const int c0 = lane * 2;
    if (c0 < NT * 16) {
        float2 bv = {0.f, 0.f};
        if (bias) {
            if (c0 < Nn)     bv.x = bias[c0];
            if (c0 + 1 < Nn) bv.y = bias[c0 + 1];
        }
        #pragma unroll
        for (int rl = 0; rl < 16; ++rl) {
            int rowD = rowbase + rl;
            if (rowD >= M) continue;
            float2 v = *(const float2*)&accL[(wave * 16 + rl) * CW + c0];
            long long o = (long long)rowD * ldc + c0;
            if (EPI == 2) {
                ushort2 hp = *(const ushort2*)&hprevB[o];
                ushort2 ag = *(const ushort2*)&aggB[o];
                v.x = bf2f(hp.x) + EPSC * tanhf(v.x + bf2f(ag.x) + bv.x);
                v.y = bf2f(hp.y) + EPSC * tanhf(v.y + bf2f(ag.y) + bv.y);
            } else {
                v.x += bv.x; v.y += bv.y;
                if (EPI == 1) {
                    v.x = v.x > 0.f ? v.x : 0.01f * v.x;
                    v.y = v.y > 0.f ? v.y : 0.01f * v.y;
                }
            }
            if (c0 + 1 < Nn) {
                if (outB) { ushort2 ob; ob.x = f2bf(v.x); ob.y = f2bf(v.y);
                            *(ushort2*)&outB[o] = ob; }
                if (outF) { *(float2*)&outF[o] = v; }
            } else if (c0 < Nn) {
                if (outB) outB[o] = f2bf(v.x);
                if (outF) outF[o] = v.x;
            }
        }
    }
}

// ---- CSR gather (bf16 in/out): one wave per node, two 32-lane halves each
// process one neighbor per iteration; xor-reduce at the end. Self loop incl.
template<int HD>
__global__ __launch_bounds__(256) void gather_kernel(
    const int* __restrict__ rowptr, const int* __restrict__ col,
    const float* __restrict__ wcsr, const float* __restrict__ dinv,
    const u16* __restrict__ gB, u16* __restrict__ aggB)
{
    int node = (blockIdx.x * 256 + threadIdx.x) >> 6;
    int lane = threadIdx.x & 63;
    if (node >= NNODE) return;
    const int half = lane >> 5, l5 = lane & 31;
    const int r0 = rowptr[node], r1 = rowptr[node + 1];
    const float wself = dinv[node] * dinv[node];

    float a0 = 0.f, a1 = 0.f, a2 = 0.f, a3 = 0.f;
    if (half == 0) {
        if (HD == 128) {
            ushort4 gs = *(const ushort4*)&gB[(long long)node * 128 + l5 * 4];
            a0 = bf2f(gs.x) * wself; a1 = bf2f(gs.y) * wself;
            a2 = bf2f(gs.z) * wself; a3 = bf2f(gs.w) * wself;
        } else {
            ushort2 gs = *(const ushort2*)&gB[(long long)node * 64 + l5 * 2];
            a0 = bf2f(gs.x) * wself; a1 = bf2f(gs.y) * wself;
        }
    }

    for (int base = r0; base < r1; base += 64) {
        int idx = base + lane;
        int cs = 0; float cw = 0.f;
        if (idx < r1) { cs = col[idx]; cw = wcsr[idx]; }
        int cnt = min(64, r1 - base);
        for (int j = 0; j < cnt; j += 2) {
            int jj = j + half;                 // <= 63 always (cnt<=64)
            int   s = __shfl(cs, jj);          // cs=0,cw=0 beyond cnt -> harmless
            float w = __shfl(cw, jj);
            if (HD == 128) {
                ushort4 gv = *(const ushort4*)&gB[(long long)s * 128 + l5 * 4];
                a0 += bf2f(gv.x) * w; a1 += bf2f(gv.y) * w;
                a2 += bf2f(gv.z) * w; a3 += bf2f(gv.w) * w;
            } else {
                ushort2 gv = *(const ushort2*)&gB[(long long)s * 64 + l5 * 2];
                a0 += bf2f(gv.x) * w; a1 += bf2f(gv.y) * w;
            }
        }
    }

    a0 += __shfl_xor(a0, 32); a1 += __shfl_xor(a1, 32);
    if (HD == 128) { a2 += __shfl_xor(a2, 32); a3 += __shfl_xor(a3, 32); }

    if (half == 0) {
        if (HD == 128) {
            ushort4 o;
            o.x = f2bf(a0); o.y = f2bf(a1); o.z = f2bf(a2); o.w = f2bf(a3);
            *(ushort4*)&aggB[(long long)node * 128 + l5 * 4] = o;
        } else {
            ushort2 o;
            o.x = f2bf(a0); o.y = f2bf(a1);
            *(ushort2*)&aggB[(long long)node * 64 + l5 * 2] = o;
        }
    }
}

// ---- log_softmax over 40 classes, one wave per row, fp32 out ----
__global__ __launch_bounds__(256) void lsm_kernel(const float* __restrict__ z,
                                                  float* __restrict__ out)
{
    int gid = blockIdx.x * 256 + threadIdx.x;
    int row = gid >> 6;
    int lane = gid & 63;
    if (row >= NNODE) return;
    float v = (lane < 40) ? z[row * 40 + lane] : -1e30f;
    float m = v;
    #pragma unroll
    for (int o = 32; o > 0; o >>= 1) m = fmaxf(m, __shfl_xor(m, o));
    float e = (lane < 40) ? expf(v - m) : 0.f;
    float s = e;
    #pragma unroll
    for (int o = 32; o > 0; o >>= 1) s += __shfl_xor(s, o);
    float l = logf(s);
    if (lane < 40) out[row * 40 + lane] = v - m - l;
}

extern "C" void kernel_launch(void* const* d_in, const int* in_sizes, int n_in,
                              void* d_out, int out_size, void* d_ws, size_t ws_size,
                              hipStream_t stream) {
    const float* x     = (const float*)d_in[0];
    const int*   ei    = (const int*)d_in[1];
    const float* w_hid = (const float*)d_in[2];
    const float* b_hid = (const float*)d_in[3];
    const float* W_a1  = (const float*)d_in[4];
    const float* gcn1  = (const float*)d_in[5];
    const float* b_a1  = (const float*)d_in[6];
    const float* w2    = (const float*)d_in[7];
    const float* b2    = (const float*)d_in[8];
    const float* W_a2  = (const float*)d_in[9];
    const float* gcn2  = (const float*)d_in[10];
    const float* b_a2  = (const float*)d_in[11];
    const float* wfc   = (const float*)d_in[12];
    const float* bfc   = (const float*)d_in[13];
    float* ws = (float*)d_ws;
    float* out = (float*)d_out;

    float* dinv   = ws + O_DINV;
    int*   degi   = (int*)(ws + O_DEGI);
    int*   rowptr = (int*)(ws + O_ROWPTR);
    int*   cursor = (int*)(ws + O_CURSOR);
    int*   psum   = (int*)(ws + O_PSUM);
    int*   col    = (int*)(ws + O_COL);
    float* wcsr   = ws + O_WCSR;
    u16* whB  = (u16*)(ws + O_WHB);
    u16* g1tB = (u16*)(ws + O_G1TB);
    u16* aw1B = (u16*)(ws + O_AW1B);
    u16* w2B  = (u16*)(ws + O_W2B);
    u16* aw2B = (u16*)(ws + O_AW2B);
    u16* g2tB = (u16*)(ws + O_G2TB);
    u16* wfcB = (u16*)(ws + O_WFCB);
    float* zF  = ws + O_Z;
    u16* gBuf = (u16*)(ws + O_GB);
    u16* aggB = (u16*)(ws + O_AGGB);
    u16* hB0  = (u16*)(ws + O_HB0);
    u16* hB1  = (u16*)(ws + O_HB1);

    const int nScanB = (NNODE + 255) / 256;  // 196

    prep_kernel<<<(84480 + 255) / 256, 256, 0, stream>>>(w_hid, W_a1, gcn1, w2, W_a2, gcn2, wfc, ws);
    zeroi_kernel<<<nScanB, 256, 0, stream>>>(degi, NNODE);
    deg_count_kernel<<<(NEDGE + 255) / 256, 256, 0, stream>>>(ei, degi);
    deg_inv_kernel<<<nScanB, 256, 0, stream>>>(degi, dinv);
    psum_kernel<<<nScanB, 256, 0, stream>>>(degi, psum);
    scan_psum_kernel<<<1, 256, 0, stream>>>(psum, nScanB);
    scan_apply_kernel<<<nScanB, 256, 0, stream>>>(degi, psum, rowptr, cursor);
    fill_kernel<<<(NEDGE + 255) / 256, 256, 0, stream>>>(ei, dinv, cursor, col, wcsr);

    const int gB = (NNODE + 63) / 64;       // 782 row-blocks
    const int gatherBlocks = (NNODE * 64 + 255) / 256;

    // h = leaky_relu(x @ w_hid^T + b_hid) -> hB0 (fp32 A converted on load)
    mgemm<8, 8, 1, 0, 1><<<gB, 256, 0, stream>>>(
        x, whB, b_hid, nullptr, nullptr, nullptr, hB0, NNODE, 128, 128);

    // conv1: 3 iterations (all-bf16 residual pipeline)
    u16* hBc = hB0; u16* hBo = hB1;
    for (int it = 0; it < 3; ++it) {
        mgemm<4, 8, 0, 0, 0><<<gB, 256, 0, stream>>>(
            hBc, g1tB, nullptr, nullptr, nullptr, nullptr, gBuf, NNODE, 128, 128);
        gather_kernel<128><<<gatherBlocks, 256, 0, stream>>>(
            rowptr, col, wcsr, dinv, gBuf, aggB);
        mgemm<4, 8, 0, 0, 2><<<gB, 256, 0, stream>>>(
            hBc, aw1B, b_a1, aggB, hBc, nullptr, hBo, NNODE, 128, 128);
        u16* tb = hBc; hBc = hBo; hBo = tb;
    }

    // h2 = leaky_relu(leaky_relu(h) @ w2^T + b2) -> hBo
    mgemm<4, 4, 0, 1, 1><<<gB, 256, 0, stream>>>(
        hBc, w2B, b2, nullptr, nullptr, nullptr, hBo, NNODE, 64, 64);
    u16* h2B = hBo;
    u16* spB = hBc;   // dead, reusable

    // conv2: 1 iteration
    mgemm<2, 4, 0, 0, 0><<<gB, 256, 0, stream>>>(
        h2B, g2tB, nullptr, nullptr, nullptr, nullptr, gBuf, NNODE, 64, 64);
    gather_kernel<64><<<gatherBlocks, 256, 0, stream>>>(
        rowptr, col, wcsr, dinv, gBuf, aggB);
    mgemm<2, 4, 0, 0, 2><<<gB, 256, 0, stream>>>(
        h2B, aw2B, b_a2, aggB, h2B, nullptr, spB, NNODE, 64, 64);

    // z = h2n @ w_fc^T + b_fc -> zF (fp32)
    mgemm<2, 3, 0, 0, 0><<<gB, 256, 0, stream>>>(
        spB, wfcB, bfc, nullptr, nullptr, zF, nullptr, NNODE, 40, 40);

    lsm_kernel<<<(NNODE * 64 + 255) / 256, 256, 0, stream>>>(zF, out);
}

// Round 10
// 472.818 us; speedup vs baseline: 3.8655x; 1.0481x over previous
//
#include <hip/hip_runtime.h>
#include <hip/hip_bf16.h>
#include <math.h>

typedef unsigned short u16;
using short8  = __attribute__((ext_vector_type(8))) short;
using ushort8 = __attribute__((ext_vector_type(8))) unsigned short;
using f32x4   = __attribute__((ext_vector_type(4))) float;

static constexpr int NNODE = 50000;
static constexpr int NEDGE = 600000;
static constexpr float EPSC   = 0.1f;
static constexpr float GAMMAC = 0.1f;

// ---- workspace layout (float-index offsets) ----
static constexpr long long O_DINV   = 0;                         // float 50000
static constexpr long long O_DEGI   = 50000;                     // int 50000
static constexpr long long O_ROWPTR = 100000;                    // int 50001
static constexpr long long O_CURSOR = 150004;                    // int 50000
static constexpr long long O_PSUM   = 200004;                    // int 256
static constexpr long long O_ECSR   = 200260;                    // int2 600000 (1.2M fl)
// bf16 weights (float slots = bf16count/2)
static constexpr long long O_WHB    = 1400260;                   // 32768 bf16
static constexpr long long O_G1TB   = O_WHB  + 16384;            // 16384 bf16
static constexpr long long O_AW1B   = O_G1TB + 8192;             // 16384 bf16
static constexpr long long O_W2B    = O_AW1B + 8192;             // 8192 bf16
static constexpr long long O_AW2B   = O_W2B  + 4096;             // 4096 bf16
static constexpr long long O_G2TB   = O_AW2B + 2048;             // 4096 bf16
static constexpr long long O_WFCB   = O_G2TB + 2048;             // 2560 bf16
// big buffers (bf16 activations; fp32 only for final z)
static constexpr long long O_Z      = 1450000;                   // float 2.0M
static constexpr long long O_GB     = 3450004;                   // bf16 6.4M (3.2M fl)
static constexpr long long O_AGGB   = O_GB   + 3200000;          // bf16 6.4M
static constexpr long long O_HB0    = O_AGGB + 3200000;          // bf16 6.4M
static constexpr long long O_HB1    = O_HB0  + 3200000;          // bf16 6.4M

__device__ __forceinline__ float bf2f(u16 u) {
    return __uint_as_float(((unsigned)u) << 16);
}
__device__ __forceinline__ u16 f2bf(float f) {
    unsigned u = __float_as_uint(f);
    return (u16)((u + 0x7FFFu + ((u >> 16) & 1u)) >> 16);
}

// ---- weight prep: antisymmetrize / transpose, all to bf16 ----
__global__ __launch_bounds__(256) void prep_kernel(
    const float* __restrict__ w_hid, const float* __restrict__ W_a1,
    const float* __restrict__ gcn1,  const float* __restrict__ w2,
    const float* __restrict__ W_a2,  const float* __restrict__ gcn2,
    const float* __restrict__ wfc,   float* __restrict__ ws)
{
    int j = blockIdx.x * 256 + threadIdx.x;
    if (j < 32768) { ((u16*)(ws+O_WHB))[j] = f2bf(w_hid[j]); return; } j -= 32768;
    if (j < 16384) { int r=j>>7, c=j&127; ((u16*)(ws+O_G1TB))[j] = f2bf(gcn1[c*128+r]); return; } j -= 16384;
    if (j < 16384) { int r=j>>7, c=j&127;
                     ((u16*)(ws+O_AW1B))[j] = f2bf(W_a1[r*128+c] - W_a1[c*128+r] - (r==c?GAMMAC:0.f));
                     return; } j -= 16384;
    if (j < 8192)  { ((u16*)(ws+O_W2B))[j] = f2bf(w2[j]); return; } j -= 8192;
    if (j < 4096)  { int r=j>>6, c=j&63;
                     ((u16*)(ws+O_AW2B))[j] = f2bf(W_a2[r*64+c] - W_a2[c*64+r] - (r==c?GAMMAC:0.f));
                     return; } j -= 4096;
    if (j < 4096)  { int r=j>>6, c=j&63; ((u16*)(ws+O_G2TB))[j] = f2bf(gcn2[c*64+r]); return; } j -= 4096;
    if (j < 2560)  { ((u16*)(ws+O_WFCB))[j] = f2bf(wfc[j]); return; }
}

// ---- CSR build ----
__global__ __launch_bounds__(256) void zeroi_kernel(int* __restrict__ p, int n) {
    int i = blockIdx.x * 256 + threadIdx.x;
    if (i < n) p[i] = 0;
}
__global__ __launch_bounds__(256) void deg_count_kernel(const int* __restrict__ ei,
                                                        int* __restrict__ degi) {
    int e = blockIdx.x * 256 + threadIdx.x;
    if (e < NEDGE) atomicAdd(&degi[ei[NEDGE + e]], 1);
}
__global__ __launch_bounds__(256) void deg_inv_kernel(const int* __restrict__ degi,
                                                      float* __restrict__ dinv) {
    int i = blockIdx.x * 256 + threadIdx.x;
    if (i < NNODE) dinv[i] = rsqrtf(1.0f + (float)degi[i]);  // +1 self loop
}
// hierarchical scan: 196-block partials -> 1-block scan -> 196-block apply
__global__ __launch_bounds__(256) void psum_kernel(const int* __restrict__ degi,
                                                   int* __restrict__ psum) {
    int i = blockIdx.x * 256 + threadIdx.x;
    int v = (i < NNODE) ? degi[i] : 0;
    #pragma unroll
    for (int o = 32; o > 0; o >>= 1) v += __shfl_xor(v, o);
    __shared__ int s[4];
    int lane = threadIdx.x & 63, w = threadIdx.x >> 6;
    if (lane == 0) s[w] = v;
    __syncthreads();
    if (threadIdx.x == 0) psum[blockIdx.x] = s[0] + s[1] + s[2] + s[3];
}
__global__ __launch_bounds__(256) void scan_psum_kernel(int* __restrict__ psum, int nb) {
    int t = threadIdx.x;
    int v = (t < nb) ? psum[t] : 0;
    int lane = t & 63, w = t >> 6;
    int x = v;
    #pragma unroll
    for (int o = 1; o < 64; o <<= 1) { int u = __shfl_up(x, o); if (lane >= o) x += u; }
    __shared__ int ws4[4];
    if (lane == 63) ws4[w] = x;
    __syncthreads();
    int woff = 0;
    for (int i = 0; i < w; ++i) woff += ws4[i];
    psum[t] = woff + x - v;   // exclusive
}
__global__ __launch_bounds__(256) void scan_apply_kernel(const int* __restrict__ degi,
                                                         const int* __restrict__ psum,
                                                         int* __restrict__ rowptr,
                                                         int* __restrict__ cursor) {
    int i = blockIdx.x * 256 + threadIdx.x;
    int v = (i < NNODE) ? degi[i] : 0;
    int lane = threadIdx.x & 63, w = threadIdx.x >> 6;
    int x = v;
    #pragma unroll
    for (int o = 1; o < 64; o <<= 1) { int u = __shfl_up(x, o); if (lane >= o) x += u; }
    __shared__ int ws4[4];
    if (lane == 63) ws4[w] = x;
    __syncthreads();
    int woff = 0;
    for (int k = 0; k < w; ++k) woff += ws4[k];
    int run = psum[blockIdx.x] + woff + x - v;
    if (i < NNODE) { rowptr[i] = run; cursor[i] = run; }
    if (i == NNODE - 1) rowptr[NNODE] = run + v;
}
// packed fill: one 8B store per edge {src, bitcast(weight)}
__global__ __launch_bounds__(256) void fill_kernel(const int* __restrict__ ei,
                                                   const float* __restrict__ dinv,
                                                   int* __restrict__ cursor,
                                                   int2* __restrict__ ecsr) {
    int e = blockIdx.x * 256 + threadIdx.x;
    if (e >= NEDGE) return;
    int s = ei[e], d = ei[NEDGE + e];
    int pos = atomicAdd(&cursor[d], 1);
    int2 v;
    v.x = s;
    v.y = __float_as_int(dinv[s] * dinv[d]);
    ecsr[pos] = v;
}

// ---- MFMA GEMM v2: LDS-staged B, LDS-transposed epilogue ----
// Block = 256 threads (4 waves), 64 rows/block, full Nn per wave.
// EPI: 0 none(+bias), 1 leaky(+bias), 2: h + EPS*tanh(acc + agg + bias).
template<int KS, int NT, int AF32, int LOADACT, int EPI>
__global__ __launch_bounds__(256, 4) void mgemm(
    const void* __restrict__ Araw,
    const u16* __restrict__ Bt,
    const float* __restrict__ bias,
    const u16* __restrict__ aggB,
    const u16* __restrict__ hprevB,
    float* __restrict__ outF,
    u16* __restrict__ outB,
    int M, int Nn, int ldc)
{
    constexpr int K    = KS * 32;
    constexpr int KCHU = (K > 128) ? 128 : K;   // B chunk width (u16 cols)
    constexpr int KC   = KCHU / 32;             // MFMA steps per chunk
    constexpr int NCH  = K / KCHU;              // chunks
    constexpr int P    = KCHU + 8;              // LDS row pitch (u16), 16B-aligned
    constexpr int ROWS = NT * 16;               // B rows staged
    constexpr int CW   = NT * 16 + 1;           // acc LDS row pitch (f32)
    constexpr int BSZ  = ROWS * P * 2;
    constexpr int ASZ  = 64 * CW * 4;
    constexpr int SMEM = BSZ > ASZ ? BSZ : ASZ;
    __shared__ __align__(16) char smem[SMEM];
    u16*   bl   = (u16*)smem;
    float* accL = (float*)smem;

    const int wave = threadIdx.x >> 6;
    const int lane = threadIdx.x & 63;
    const int m = lane & 15, q = lane >> 4;
    const int rowbase = blockIdx.x * 64 + wave * 16;
    const int row = rowbase + m;
    const bool rok = row < M;
    const short8 z8 = {0,0,0,0,0,0,0,0};

    // A fragments for this wave's 16 rows
    short8 af[KS];
    if (AF32) {
        const float* apf = (const float*)Araw + (long long)row * K;
        #pragma unroll
        for (int k = 0; k < KS; ++k) {
            short8 t = z8;
            if (rok) {
                const float4* p = (const float4*)(apf + (k * 4 + q) * 8);
                float4 a = p[0], b = p[1];
                t[0]=(short)f2bf(a.x); t[1]=(short)f2bf(a.y); t[2]=(short)f2bf(a.z); t[3]=(short)f2bf(a.w);
                t[4]=(short)f2bf(b.x); t[5]=(short)f2bf(b.y); t[6]=(short)f2bf(b.z); t[7]=(short)f2bf(b.w);
            }
            af[k] = t;
        }
    } else {
        const short8* ap = (const short8*)((const u16*)Araw + (long long)row * K);
        #pragma unroll
        for (int k = 0; k < KS; ++k) af[k] = rok ? ap[k * 4 + q] : z8;
    }
    if (LOADACT) {
        #pragma unroll
        for (int k = 0; k < KS; ++k)
            #pragma unroll
            for (int e = 0; e < 8; ++e) {
                float f = bf2f((u16)af[k][e]);
                f = f > 0.f ? f : 0.01f * f;
                af[k][e] = (short)f2bf(f);
            }
    }

    f32x4 acc[NT];
    #pragma unroll
    for (int j = 0; j < NT; ++j) acc[j] = (f32x4){0.f,0.f,0.f,0.f};

    for (int ch = 0; ch < NCH; ++ch) {
        if (ch) __syncthreads();
        constexpr int CHUNKS = ROWS * (KCHU / 8);
        for (int t = threadIdx.x; t < CHUNKS; t += 256) {
            int r = t / (KCHU / 8), c = t - r * (KCHU / 8);
            short8 v = z8;
            if (r < Nn) v = *(const short8*)&Bt[(long long)r * K + ch * KCHU + c * 8];
            *(short8*)&bl[r * P + c * 8] = v;
        }
        __syncthreads();
        #pragma unroll
        for (int j = 0; j < NT; ++j) {
            #pragma unroll
            for (int k = 0; k < KC; ++k) {
                short8 bf_ = *(const short8*)&bl[(j * 16 + m) * P + k * 32 + q * 8];
                acc[j] = __builtin_amdgcn_mfma_f32_16x16x32_bf16(af[ch * KC + k], bf_, acc[j], 0, 0, 0);
            }
        }
    }

    __syncthreads();            // reuse LDS for acc transpose
    #pragma unroll
    for (int j = 0; j < NT; ++j)
        #pragma unroll
        for (int r = 0; r < 4; ++r)
            accL[(wave * 16 + q * 4 + r) * CW + j * 16 + m] = acc[j][r];
    __syncthreads();

    const int c0 = lane * 2;
    if (c0 < NT * 16) {
        float2 bv = {0.f, 0.f};
        if (bias) {
            if (c0 < Nn)     bv.x = bias[c0];
            if (c0 + 1 < Nn) bv.y = bias[c0 + 1];
        }
        #pragma unroll
        for (int rl = 0; rl < 16; ++rl) {
            int rowD = rowbase + rl;
            if (rowD >= M) continue;
            float2 v = *(const float2*)&accL[(wave * 16 + rl) * CW + c0];
            long long o = (long long)rowD * ldc + c0;
            if (EPI == 2) {
                ushort2 hp = *(const ushort2*)&hprevB[o];
                ushort2 ag = *(const ushort2*)&aggB[o];
                v.x = bf2f(hp.x) + EPSC * tanhf(v.x + bf2f(ag.x) + bv.x);
                v.y = bf2f(hp.y) + EPSC * tanhf(v.y + bf2f(ag.y) + bv.y);
            } else {
                v.x += bv.x; v.y += bv.y;
                if (EPI == 1) {
                    v.x = v.x > 0.f ? v.x : 0.01f * v.x;
                    v.y = v.y > 0.f ? v.y : 0.01f * v.y;
                }
            }
            if (c0 + 1 < Nn) {
                if (outB) { ushort2 ob; ob.x = f2bf(v.x); ob.y = f2bf(v.y);
                            *(ushort2*)&outB[o] = ob; }
                if (outF) { *(float2*)&outF[o] = v; }
            } else if (c0 < Nn) {
                if (outB) outB[o] = f2bf(v.x);
                if (outF) outF[o] = v.x;
            }
        }
    }
}

// ---- CSR gather (bf16, packed edges): one wave per node, four 16-lane
// quarters each process one neighbor per iter with 16B loads; xor-reduce.
template<int HD>
__global__ __launch_bounds__(256) void gather_kernel(
    const int* __restrict__ rowptr, const int2* __restrict__ ecsr,
    const float* __restrict__ dinv,
    const u16* __restrict__ gB, u16* __restrict__ aggB)
{
    int node = (blockIdx.x * 256 + threadIdx.x) >> 6;
    int lane = threadIdx.x & 63;
    if (node >= NNODE) return;
    const int qr = lane >> 4, l4 = lane & 15;
    const int r0 = rowptr[node], r1 = rowptr[node + 1];
    const float wself = dinv[node] * dinv[node];
    constexpr int EL = (HD == 128) ? 8 : 4;   // bf16 elems per lane

    float a[EL];
    #pragma unroll
    for (int i = 0; i < EL; ++i) a[i] = 0.f;
    if (qr == 0) {
        if (HD == 128) {
            ushort8 gs = *(const ushort8*)&gB[(long long)node * 128 + l4 * 8];
            #pragma unroll
            for (int i = 0; i < 8; ++i) a[i] = bf2f(gs[i]) * wself;
        } else {
            ushort4 gs = *(const ushort4*)&gB[(long long)node * 64 + l4 * 4];
            a[0] = bf2f(gs.x) * wself; a[1] = bf2f(gs.y) * wself;
            a[2] = bf2f(gs.z) * wself; a[3] = bf2f(gs.w) * wself;
        }
    }

    for (int base = r0; base < r1; base += 64) {
        int idx = base + lane;
        int cs = 0; float cw = 0.f;
        if (idx < r1) { int2 ev = ecsr[idx]; cs = ev.x; cw = __int_as_float(ev.y); }
        int cnt = min(64, r1 - base);
        for (int j = 0; j < cnt; j += 4) {
            int jj = j + qr;                    // <= 63; lanes beyond cnt have cw=0
            int   s = __shfl(cs, jj);
            float w = __shfl(cw, jj);
            if (HD == 128) {
                ushort8 gv = *(const ushort8*)&gB[(long long)s * 128 + l4 * 8];
                #pragma unroll
                for (int i = 0; i < 8; ++i) a[i] += bf2f(gv[i]) * w;
            } else {
                ushort4 gv = *(const ushort4*)&gB[(long long)s * 64 + l4 * 4];
                a[0] += bf2f(gv.x) * w; a[1] += bf2f(gv.y) * w;
                a[2] += bf2f(gv.z) * w; a[3] += bf2f(gv.w) * w;
            }
        }
    }

    #pragma unroll
    for (int i = 0; i < EL; ++i) {
        a[i] += __shfl_xor(a[i], 16);
        a[i] += __shfl_xor(a[i], 32);
    }

    if (qr == 0) {
        if (HD == 128) {
            ushort8 o;
            #pragma unroll
            for (int i = 0; i < 8; ++i) o[i] = f2bf(a[i]);
            *(ushort8*)&aggB[(long long)node * 128 + l4 * 8] = o;
        } else {
            ushort4 o;
            o.x = f2bf(a[0]); o.y = f2bf(a[1]); o.z = f2bf(a[2]); o.w = f2bf(a[3]);
            *(ushort4*)&aggB[(long long)node * 64 + l4 * 4] = o;
        }
    }
}

// ---- log_softmax over 40 classes, one wave per row, fp32 out ----
__global__ __launch_bounds__(256) void lsm_kernel(const float* __restrict__ z,
                                                  float* __restrict__ out)
{
    int gid = blockIdx.x * 256 + threadIdx.x;
    int row = gid >> 6;
    int lane = gid & 63;
    if (row >= NNODE) return;
    float v = (lane < 40) ? z[row * 40 + lane] : -1e30f;
    float m = v;
    #pragma unroll
    for (int o = 32; o > 0; o >>= 1) m = fmaxf(m, __shfl_xor(m, o));
    float e = (lane < 40) ? expf(v - m) : 0.f;
    float s = e;
    #pragma unroll
    for (int o = 32; o > 0; o >>= 1) s += __shfl_xor(s, o);
    float l = logf(s);
    if (lane < 40) out[row * 40 + lane] = v - m - l;
}

extern "C" void kernel_launch(void* const* d_in, const int* in_sizes, int n_in,
                              void* d_out, int out_size, void* d_ws, size_t ws_size,
                              hipStream_t stream) {
    const float* x     = (const float*)d_in[0];
    const int*   ei    = (const int*)d_in[1];
    const float* w_hid = (const float*)d_in[2];
    const float* b_hid = (const float*)d_in[3];
    const float* W_a1  = (const float*)d_in[4];
    const float* gcn1  = (const float*)d_in[5];
    const float* b_a1  = (const float*)d_in[6];
    const float* w2    = (const float*)d_in[7];
    const float* b2    = (const float*)d_in[8];
    const float* W_a2  = (const float*)d_in[9];
    const float* gcn2  = (const float*)d_in[10];
    const float* b_a2  = (const float*)d_in[11];
    const float* wfc   = (const float*)d_in[12];
    const float* bfc   = (const float*)d_in[13];
    float* ws = (float*)d_ws;
    float* out = (float*)d_out;

    float* dinv   = ws + O_DINV;
    int*   degi   = (int*)(ws + O_DEGI);
    int*   rowptr = (int*)(ws + O_ROWPTR);
    int*   cursor = (int*)(ws + O_CURSOR);
    int*   psum   = (int*)(ws + O_PSUM);
    int2*  ecsr   = (int2*)(ws + O_ECSR);
    u16* whB  = (u16*)(ws + O_WHB);
    u16* g1tB = (u16*)(ws + O_G1TB);
    u16* aw1B = (u16*)(ws + O_AW1B);
    u16* w2B  = (u16*)(ws + O_W2B);
    u16* aw2B = (u16*)(ws + O_AW2B);
    u16* g2tB = (u16*)(ws + O_G2TB);
    u16* wfcB = (u16*)(ws + O_WFCB);
    float* zF  = ws + O_Z;
    u16* gBuf = (u16*)(ws + O_GB);
    u16* aggB = (u16*)(ws + O_AGGB);
    u16* hB0  = (u16*)(ws + O_HB0);
    u16* hB1  = (u16*)(ws + O_HB1);

    const int nScanB = (NNODE + 255) / 256;  // 196

    prep_kernel<<<(84480 + 255) / 256, 256, 0, stream>>>(w_hid, W_a1, gcn1, w2, W_a2, gcn2, wfc, ws);
    zeroi_kernel<<<nScanB, 256, 0, stream>>>(degi, NNODE);
    deg_count_kernel<<<(NEDGE + 255) / 256, 256, 0, stream>>>(ei, degi);
    deg_inv_kernel<<<nScanB, 256, 0, stream>>>(degi, dinv);
    psum_kernel<<<nScanB, 256, 0, stream>>>(degi, psum);
    scan_psum_kernel<<<1, 256, 0, stream>>>(psum, nScanB);
    scan_apply_kernel<<<nScanB, 256, 0, stream>>>(degi, psum, rowptr, cursor);
    fill_kernel<<<(NEDGE + 255) / 256, 256, 0, stream>>>(ei, dinv, cursor, ecsr);

    const int gB = (NNODE + 63) / 64;       // 782 row-blocks
    const int gatherBlocks = (NNODE * 64 + 255) / 256;

    // h = leaky_relu(x @ w_hid^T + b_hid) -> hB0 (fp32 A converted on load)
    mgemm<8, 8, 1, 0, 1><<<gB, 256, 0, stream>>>(
        x, whB, b_hid, nullptr, nullptr, nullptr, hB0, NNODE, 128, 128);

    // conv1: 3 iterations (all-bf16 residual pipeline)
    u16* hBc = hB0; u16* hBo = hB1;
    for (int it = 0; it < 3; ++it) {
        mgemm<4, 8, 0, 0, 0><<<gB, 256, 0, stream>>>(
            hBc, g1tB, nullptr, nullptr, nullptr, nullptr, gBuf, NNODE, 128, 128);
        gather_kernel<128><<<gatherBlocks, 256, 0, stream>>>(
            rowptr, ecsr, dinv, gBuf, aggB);
        mgemm<4, 8, 0, 0, 2><<<gB, 256, 0, stream>>>(
            hBc, aw1B, b_a1, aggB, hBc, nullptr, hBo, NNODE, 128, 128);
        u16* tb = hBc; hBc = hBo; hBo = tb;
    }

    // h2 = leaky_relu(leaky_relu(h) @ w2^T + b2) -> hBo
    mgemm<4, 4, 0, 1, 1><<<gB, 256, 0, stream>>>(
        hBc, w2B, b2, nullptr, nullptr, nullptr, hBo, NNODE, 64, 64);
    u16* h2B = hBo;
    u16* spB = hBc;   // dead, reusable

    // conv2: 1 iteration
    mgemm<2, 4, 0, 0, 0><<<gB, 256, 0, stream>>>(
        h2B, g2tB, nullptr, nullptr, nullptr, nullptr, gBuf, NNODE, 64, 64);
    gather_kernel<64><<<gatherBlocks, 256, 0, stream>>>(
        rowptr, ecsr, dinv, gBuf, aggB);
    mgemm<2, 4, 0, 0, 2><<<gB, 256, 0, stream>>>(
        h2B, aw2B, b_a2, aggB, h2B, nullptr, spB, NNODE, 64, 64);

    // z = h2n @ w_fc^T + b_fc -> zF (fp32)
    mgemm<2, 3, 0, 0, 0><<<gB, 256, 0, stream>>>(
        spB, wfcB, bfc, nullptr, nullptr, zF, nullptr, NNODE, 40, 40);

    lsm_kernel<<<(NNODE * 64 + 255) / 256, 256, 0, stream>>>(zF, out);
}

// Round 11
// 464.859 us; speedup vs baseline: 3.9317x; 1.0171x over previous
//
#include <hip/hip_runtime.h>
#include <hip/hip_bf16.h>
#include <math.h>

typedef unsigned short u16;
using short8  = __attribute__((ext_vector_type(8))) short;
using ushort8 = __attribute__((ext_vector_type(8))) unsigned short;
using f32x4   = __attribute__((ext_vector_type(4))) float;

static constexpr int NNODE = 50000;
static constexpr int NEDGE = 600000;
static constexpr float EPSC   = 0.1f;
static constexpr float GAMMAC = 0.1f;

// ---- workspace layout (float-index offsets) ----
static constexpr long long O_DINV   = 0;                         // float 50000
static constexpr long long O_DEGI   = 50000;                     // int 50000
static constexpr long long O_ROWPTR = 100000;                    // int 50001
static constexpr long long O_CURSOR = 150004;                    // int 50000
static constexpr long long O_PSUM   = 200004;                    // int 256
static constexpr long long O_ECSR   = 200260;                    // int2 600000 (1.2M fl)
// bf16 weights (float slots = bf16count/2)
static constexpr long long O_WHB    = 1400260;                   // 32768 bf16
static constexpr long long O_G1TB   = O_WHB  + 16384;            // 16384 bf16
static constexpr long long O_AW1B   = O_G1TB + 8192;             // 16384 bf16
static constexpr long long O_W2B    = O_AW1B + 8192;             // 8192 bf16
static constexpr long long O_AW2B   = O_W2B  + 4096;             // 4096 bf16
static constexpr long long O_G2TB   = O_AW2B + 2048;             // 4096 bf16
static constexpr long long O_WFCB   = O_G2TB + 2048;             // 2560 bf16
// big buffers (bf16 activations)
static constexpr long long O_GB     = 3450004;                   // bf16 6.4M (3.2M fl)
static constexpr long long O_AGGB   = O_GB   + 3200000;          // bf16 6.4M
static constexpr long long O_HB0    = O_AGGB + 3200000;          // bf16 6.4M
static constexpr long long O_HB1    = O_HB0  + 3200000;          // bf16 6.4M

__device__ __forceinline__ float bf2f(u16 u) {
    return __uint_as_float(((unsigned)u) << 16);
}
__device__ __forceinline__ u16 f2bf(float f) {
    unsigned u = __float_as_uint(f);
    return (u16)((u + 0x7FFFu + ((u >> 16) & 1u)) >> 16);
}

// ---- weight prep (bf16 convert/antisym/transpose) + degi zero (fused) ----
__global__ __launch_bounds__(256) void prep_kernel(
    const float* __restrict__ w_hid, const float* __restrict__ W_a1,
    const float* __restrict__ gcn1,  const float* __restrict__ w2,
    const float* __restrict__ W_a2,  const float* __restrict__ gcn2,
    const float* __restrict__ wfc,   float* __restrict__ ws)
{
    int j = blockIdx.x * 256 + threadIdx.x;
    if (j < 32768) { ((u16*)(ws+O_WHB))[j] = f2bf(w_hid[j]); return; } j -= 32768;
    if (j < 16384) { int r=j>>7, c=j&127; ((u16*)(ws+O_G1TB))[j] = f2bf(gcn1[c*128+r]); return; } j -= 16384;
    if (j < 16384) { int r=j>>7, c=j&127;
                     ((u16*)(ws+O_AW1B))[j] = f2bf(W_a1[r*128+c] - W_a1[c*128+r] - (r==c?GAMMAC:0.f));
                     return; } j -= 16384;
    if (j < 8192)  { ((u16*)(ws+O_W2B))[j] = f2bf(w2[j]); return; } j -= 8192;
    if (j < 4096)  { int r=j>>6, c=j&63;
                     ((u16*)(ws+O_AW2B))[j] = f2bf(W_a2[r*64+c] - W_a2[c*64+r] - (r==c?GAMMAC:0.f));
                     return; } j -= 4096;
    if (j < 4096)  { int r=j>>6, c=j&63; ((u16*)(ws+O_G2TB))[j] = f2bf(gcn2[c*64+r]); return; } j -= 4096;
    if (j < 2560)  { ((u16*)(ws+O_WFCB))[j] = f2bf(wfc[j]); return; } j -= 2560;
    if (j < NNODE) { ((int*)(ws+O_DEGI))[j] = 0; return; }   // fused degi zero
}

// ---- CSR build ----
__global__ __launch_bounds__(256) void deg_count_kernel(const int* __restrict__ ei,
                                                        int* __restrict__ degi) {
    int e = blockIdx.x * 256 + threadIdx.x;
    if (e < NEDGE) atomicAdd(&degi[ei[NEDGE + e]], 1);
}
// partial sums per 256-block + fused dinv compute
__global__ __launch_bounds__(256) void psum_kernel(const int* __restrict__ degi,
                                                   float* __restrict__ dinv,
                                                   int* __restrict__ psum) {
    int i = blockIdx.x * 256 + threadIdx.x;
    int v = (i < NNODE) ? degi[i] : 0;
    if (i < NNODE) dinv[i] = rsqrtf(1.0f + (float)v);  // +1 self loop
    int t = v;
    #pragma unroll
    for (int o = 32; o > 0; o >>= 1) t += __shfl_xor(t, o);
    __shared__ int s[4];
    int lane = threadIdx.x & 63, w = threadIdx.x >> 6;
    if (lane == 0) s[w] = t;
    __syncthreads();
    if (threadIdx.x == 0) psum[blockIdx.x] = s[0] + s[1] + s[2] + s[3];
}
__global__ __launch_bounds__(256) void scan_psum_kernel(int* __restrict__ psum, int nb) {
    int t = threadIdx.x;
    int v = (t < nb) ? psum[t] : 0;
    int lane = t & 63, w = t >> 6;
    int x = v;
    #pragma unroll
    for (int o = 1; o < 64; o <<= 1) { int u = __shfl_up(x, o); if (lane >= o) x += u; }
    __shared__ int ws4[4];
    if (lane == 63) ws4[w] = x;
    __syncthreads();
    int woff = 0;
    for (int i = 0; i < w; ++i) woff += ws4[i];
    psum[t] = woff + x - v;   // exclusive
}
__global__ __launch_bounds__(256) void scan_apply_kernel(const int* __restrict__ degi,
                                                         const int* __restrict__ psum,
                                                         int* __restrict__ rowptr,
                                                         int* __restrict__ cursor) {
    int i = blockIdx.x * 256 + threadIdx.x;
    int v = (i < NNODE) ? degi[i] : 0;
    int lane = threadIdx.x & 63, w = threadIdx.x >> 6;
    int x = v;
    #pragma unroll
    for (int o = 1; o < 64; o <<= 1) { int u = __shfl_up(x, o); if (lane >= o) x += u; }
    __shared__ int ws4[4];
    if (lane == 63) ws4[w] = x;
    __syncthreads();
    int woff = 0;
    for (int k = 0; k < w; ++k) woff += ws4[k];
    int run = psum[blockIdx.x] + woff + x - v;
    if (i < NNODE) { rowptr[i] = run; cursor[i] = run; }
    if (i == NNODE - 1) rowptr[NNODE] = run + v;
}
// packed fill: one 8B store per edge {src, bitcast(weight)}
__global__ __launch_bounds__(256) void fill_kernel(const int* __restrict__ ei,
                                                   const float* __restrict__ dinv,
                                                   int* __restrict__ cursor,
                                                   int2* __restrict__ ecsr) {
    int e = blockIdx.x * 256 + threadIdx.x;
    if (e >= NEDGE) return;
    int s = ei[e], d = ei[NEDGE + e];
    int pos = atomicAdd(&cursor[d], 1);
    int2 v;
    v.x = s;
    v.y = __float_as_int(dinv[s] * dinv[d]);
    ecsr[pos] = v;
}

// ---- MFMA GEMM: LDS-staged B, LDS-transposed epilogue ----
// EPI: 0 none(+bias), 1 leaky(+bias), 2: h+EPS*tanh(acc+agg+bias),
//      3: log_softmax(acc+bias) per row -> outF (fused final layer).
template<int KS, int NT, int AF32, int LOADACT, int EPI>
__global__ __launch_bounds__(256, 4) void mgemm(
    const void* __restrict__ Araw,
    const u16* __restrict__ Bt,
    const float* __restrict__ bias,
    const u16* __restrict__ aggB,
    const u16* __restrict__ hprevB,
    float* __restrict__ outF,
    u16* __restrict__ outB,
    int M, int Nn, int ldc)
{
    constexpr int K    = KS * 32;
    constexpr int KCHU = (K > 128) ? 128 : K;
    constexpr int KC   = KCHU / 32;
    constexpr int NCH  = K / KCHU;
    constexpr int P    = KCHU + 8;
    constexpr int ROWS = NT * 16;
    constexpr int CW   = NT * 16 + 1;
    constexpr int BSZ  = ROWS * P * 2;
    constexpr int ASZ  = 64 * CW * 4;
    constexpr int SMEM = BSZ > ASZ ? BSZ : ASZ;
    __shared__ __align__(16) char smem[SMEM];
    u16*   bl   = (u16*)smem;
    float* accL = (float*)smem;

    const int wave = threadIdx.x >> 6;
    const int lane = threadIdx.x & 63;
    const int m = lane & 15, q = lane >> 4;
    const int rowbase = blockIdx.x * 64 + wave * 16;
    const int row = rowbase + m;
    const bool rok = row < M;
    const short8 z8 = {0,0,0,0,0,0,0,0};

    short8 af[KS];
    if (AF32) {
        const float* apf = (const float*)Araw + (long long)row * K;
        #pragma unroll
        for (int k = 0; k < KS; ++k) {
            short8 t = z8;
            if (rok) {
                const float4* p = (const float4*)(apf + (k * 4 + q) * 8);
                float4 a = p[0], b = p[1];
                t[0]=(short)f2bf(a.x); t[1]=(short)f2bf(a.y); t[2]=(short)f2bf(a.z); t[3]=(short)f2bf(a.w);
                t[4]=(short)f2bf(b.x); t[5]=(short)f2bf(b.y); t[6]=(short)f2bf(b.z); t[7]=(short)f2bf(b.w);
            }
            af[k] = t;
        }
    } else {
        const short8* ap = (const short8*)((const u16*)Araw + (long long)row * K);
        #pragma unroll
        for (int k = 0; k < KS; ++k) af[k] = rok ? ap[k * 4 + q] : z8;
    }
    if (LOADACT) {
        #pragma unroll
        for (int k = 0; k < KS; ++k)
            #pragma unroll
            for (int e = 0; e < 8; ++e) {
                float f = bf2f((u16)af[k][e]);
                f = f > 0.f ? f : 0.01f * f;
                af[k][e] = (short)f2bf(f);
            }
    }

    f32x4 acc[NT];
    #pragma unroll
    for (int j = 0; j < NT; ++j) acc[j] = (f32x4){0.f,0.f,0.f,0.f};

    for (int ch = 0; ch < NCH; ++ch) {
        if (ch) __syncthreads();
        constexpr int CHUNKS = ROWS * (KCHU / 8);
        for (int t = threadIdx.x; t < CHUNKS; t += 256) {
            int r = t / (KCHU / 8), c = t - r * (KCHU / 8);
            short8 v = z8;
            if (r < Nn) v = *(const short8*)&Bt[(long long)r * K + ch * KCHU + c * 8];
            *(short8*)&bl[r * P + c * 8] = v;
        }
        __syncthreads();
        #pragma unroll
        for (int j = 0; j < NT; ++j) {
            #pragma unroll
            for (int k = 0; k < KC; ++k) {
                short8 bf_ = *(const short8*)&bl[(j * 16 + m) * P + k * 32 + q * 8];
                acc[j] = __builtin_amdgcn_mfma_f32_16x16x32_bf16(af[ch * KC + k], bf_, acc[j], 0, 0, 0);
            }
        }
    }

    __syncthreads();            // reuse LDS for acc transpose
    #pragma unroll
    for (int j = 0; j < NT; ++j)
        #pragma unroll
        for (int r = 0; r < 4; ++r)
            accL[(wave * 16 + q * 4 + r) * CW + j * 16 + m] = acc[j][r];
    __syncthreads();

    if (EPI == 3) {
        // fused log-softmax over the Nn columns of each row (all in LDS)
        float mrow = 0.f, lrow = 0.f;
        if (lane < 16) {
            const float* rp = &accL[(wave * 16 + lane) * CW];
            float mx = -1e30f;
            for (int c = 0; c < Nn; ++c) mx = fmaxf(mx, rp[c] + bias[c]);
            float s = 0.f;
            for (int c = 0; c < Nn; ++c) s += expf(rp[c] + bias[c] - mx);
            mrow = mx; lrow = logf(s);
        }
        for (int rl = 0; rl < 16; ++rl) {
            float mm = __shfl(mrow, rl);
            float ll = __shfl(lrow, rl);
            int rowD = rowbase + rl;
            if (rowD < M && lane < Nn) {
                float v = accL[(wave * 16 + rl) * CW + lane] + bias[lane];
                outF[(long long)rowD * ldc + lane] = v - mm - ll;
            }
        }
        return;
    }

    const int c0 = lane * 2;
    if (c0 < NT * 16) {
        float2 bv = {0.f, 0.f};
        if (bias) {
            if (c0 < Nn)     bv.x = bias[c0];
            if (c0 + 1 < Nn) bv.y = bias[c0 + 1];
        }
        #pragma unroll
        for (int rl = 0; rl < 16; ++rl) {
            int rowD = rowbase + rl;
            if (rowD >= M) continue;
            float2 v = *(const float2*)&accL[(wave * 16 + rl) * CW + c0];
            long long o = (long long)rowD * ldc + c0;
            if (EPI == 2) {
                ushort2 hp = *(const ushort2*)&hprevB[o];
                ushort2 ag = *(const ushort2*)&aggB[o];
                v.x = bf2f(hp.x) + EPSC * tanhf(v.x + bf2f(ag.x) + bv.x);
                v.y = bf2f(hp.y) + EPSC * tanhf(v.y + bf2f(ag.y) + bv.y);
            } else {
                v.x += bv.x; v.y += bv.y;
                if (EPI == 1) {
                    v.x = v.x > 0.f ? v.x : 0.01f * v.x;
                    v.y = v.y > 0.f ? v.y : 0.01f * v.y;
                }
            }
            if (c0 + 1 < Nn) {
                if (outB) { ushort2 ob; ob.x = f2bf(v.x); ob.y = f2bf(v.y);
                            *(ushort2*)&outB[o] = ob; }
                if (outF) { *(float2*)&outF[o] = v; }
            } else if (c0 < Nn) {
                if (outB) outB[o] = f2bf(v.x);
                if (outF) outF[o] = v.x;
            }
        }
    }
}

// ---- CSR gather (bf16, packed edges): four 16-lane quarters, 16B loads ----
template<int HD>
__global__ __launch_bounds__(256) void gather_kernel(
    const int* __restrict__ rowptr, const int2* __restrict__ ecsr,
    const float* __restrict__ dinv,
    const u16* __restrict__ gB, u16* __restrict__ aggB)
{
    int node = (blockIdx.x * 256 + threadIdx.x) >> 6;
    int lane = threadIdx.x & 63;
    if (node >= NNODE) return;
    const int qr = lane >> 4, l4 = lane & 15;
    const int r0 = rowptr[node], r1 = rowptr[node + 1];
    const float wself = dinv[node] * dinv[node];
    constexpr int EL = (HD == 128) ? 8 : 4;

    float a[EL];
    #pragma unroll
    for (int i = 0; i < EL; ++i) a[i] = 0.f;
    if (qr == 0) {
        if (HD == 128) {
            ushort8 gs = *(const ushort8*)&gB[(long long)node * 128 + l4 * 8];
            #pragma unroll
            for (int i = 0; i < 8; ++i) a[i] = bf2f(gs[i]) * wself;
        } else {
            ushort4 gs = *(const ushort4*)&gB[(long long)node * 64 + l4 * 4];
            a[0] = bf2f(gs.x) * wself; a[1] = bf2f(gs.y) * wself;
            a[2] = bf2f(gs.z) * wself; a[3] = bf2f(gs.w) * wself;
        }
    }

    for (int base = r0; base < r1; base += 64) {
        int idx = base + lane;
        int cs = 0; float cw = 0.f;
        if (idx < r1) { int2 ev = ecsr[idx]; cs = ev.x; cw = __int_as_float(ev.y); }
        int cnt = min(64, r1 - base);
        for (int j = 0; j < cnt; j += 4) {
            int jj = j + qr;
            int   s = __shfl(cs, jj);
            float w = __shfl(cw, jj);
            if (HD == 128) {
                ushort8 gv = *(const ushort8*)&gB[(long long)s * 128 + l4 * 8];
                #pragma unroll
                for (int i = 0; i < 8; ++i) a[i] += bf2f(gv[i]) * w;
            } else {
                ushort4 gv = *(const ushort4*)&gB[(long long)s * 64 + l4 * 4];
                a[0] += bf2f(gv.x) * w; a[1] += bf2f(gv.y) * w;
                a[2] += bf2f(gv.z) * w; a[3] += bf2f(gv.w) * w;
            }
        }
    }

    #pragma unroll
    for (int i = 0; i < EL; ++i) {
        a[i] += __shfl_xor(a[i], 16);
        a[i] += __shfl_xor(a[i], 32);
    }

    if (qr == 0) {
        if (HD == 128) {
            ushort8 o;
            #pragma unroll
            for (int i = 0; i < 8; ++i) o[i] = f2bf(a[i]);
            *(ushort8*)&aggB[(long long)node * 128 + l4 * 8] = o;
        } else {
            ushort4 o;
            o.x = f2bf(a[0]); o.y = f2bf(a[1]); o.z = f2bf(a[2]); o.w = f2bf(a[3]);
            *(ushort4*)&aggB[(long long)node * 64 + l4 * 4] = o;
        }
    }
}

extern "C" void kernel_launch(void* const* d_in, const int* in_sizes, int n_in,
                              void* d_out, int out_size, void* d_ws, size_t ws_size,
                              hipStream_t stream) {
    const float* x     = (const float*)d_in[0];
    const int*   ei    = (const int*)d_in[1];
    const float* w_hid = (const float*)d_in[2];
    const float* b_hid = (const float*)d_in[3];
    const float* W_a1  = (const float*)d_in[4];
    const float* gcn1  = (const float*)d_in[5];
    const float* b_a1  = (const float*)d_in[6];
    const float* w2    = (const float*)d_in[7];
    const float* b2    = (const float*)d_in[8];
    const float* W_a2  = (const float*)d_in[9];
    const float* gcn2  = (const float*)d_in[10];
    const float* b_a2  = (const float*)d_in[11];
    const float* wfc   = (const float*)d_in[12];
    const float* bfc   = (const float*)d_in[13];
    float* ws = (float*)d_ws;
    float* out = (float*)d_out;

    float* dinv   = ws + O_DINV;
    int*   degi   = (int*)(ws + O_DEGI);
    int*   rowptr = (int*)(ws + O_ROWPTR);
    int*   cursor = (int*)(ws + O_CURSOR);
    int*   psum   = (int*)(ws + O_PSUM);
    int2*  ecsr   = (int2*)(ws + O_ECSR);
    u16* whB  = (u16*)(ws + O_WHB);
    u16* g1tB = (u16*)(ws + O_G1TB);
    u16* aw1B = (u16*)(ws + O_AW1B);
    u16* w2B  = (u16*)(ws + O_W2B);
    u16* aw2B = (u16*)(ws + O_AW2B);
    u16* g2tB = (u16*)(ws + O_G2TB);
    u16* wfcB = (u16*)(ws + O_WFCB);
    u16* gBuf = (u16*)(ws + O_GB);
    u16* aggB = (u16*)(ws + O_AGGB);
    u16* hB0  = (u16*)(ws + O_HB0);
    u16* hB1  = (u16*)(ws + O_HB1);

    const int nScanB = (NNODE + 255) / 256;  // 196

    prep_kernel<<<(84480 + NNODE + 255) / 256, 256, 0, stream>>>(
        w_hid, W_a1, gcn1, w2, W_a2, gcn2, wfc, ws);
    deg_count_kernel<<<(NEDGE + 255) / 256, 256, 0, stream>>>(ei, degi);
    psum_kernel<<<nScanB, 256, 0, stream>>>(degi, dinv, psum);
    scan_psum_kernel<<<1, 256, 0, stream>>>(psum, nScanB);
    scan_apply_kernel<<<nScanB, 256, 0, stream>>>(degi, psum, rowptr, cursor);
    fill_kernel<<<(NEDGE + 255) / 256, 256, 0, stream>>>(ei, dinv, cursor, ecsr);

    const int gB = (NNODE + 63) / 64;       // 782 row-blocks
    const int gatherBlocks = (NNODE * 64 + 255) / 256;

    // h = leaky_relu(x @ w_hid^T + b_hid) -> hB0 (fp32 A converted on load)
    mgemm<8, 8, 1, 0, 1><<<gB, 256, 0, stream>>>(
        x, whB, b_hid, nullptr, nullptr, nullptr, hB0, NNODE, 128, 128);

    // conv1: 3 iterations (all-bf16 residual pipeline)
    u16* hBc = hB0; u16* hBo = hB1;
    for (int it = 0; it < 3; ++it) {
        mgemm<4, 8, 0, 0, 0><<<gB, 256, 0, stream>>>(
            hBc, g1tB, nullptr, nullptr, nullptr, nullptr, gBuf, NNODE, 128, 128);
        gather_kernel<128><<<gatherBlocks, 256, 0, stream>>>(
            rowptr, ecsr, dinv, gBuf, aggB);
        mgemm<4, 8, 0, 0, 2><<<gB, 256, 0, stream>>>(
            hBc, aw1B, b_a1, aggB, hBc, nullptr, hBo, NNODE, 128, 128);
        u16* tb = hBc; hBc = hBo; hBo = tb;
    }

    // h2 = leaky_relu(leaky_relu(h) @ w2^T + b2) -> hBo
    mgemm<4, 4, 0, 1, 1><<<gB, 256, 0, stream>>>(
        hBc, w2B, b2, nullptr, nullptr, nullptr, hBo, NNODE, 64, 64);
    u16* h2B = hBo;
    u16* spB = hBc;   // dead, reusable

    // conv2: 1 iteration
    mgemm<2, 4, 0, 0, 0><<<gB, 256, 0, stream>>>(
        h2B, g2tB, nullptr, nullptr, nullptr, nullptr, gBuf, NNODE, 64, 64);
    gather_kernel<64><<<gatherBlocks, 256, 0, stream>>>(
        rowptr, ecsr, dinv, gBuf, aggB);
    mgemm<2, 4, 0, 0, 2><<<gB, 256, 0, stream>>>(
        h2B, aw2B, b_a2, aggB, h2B, nullptr, spB, NNODE, 64, 64);

    // z = h2n @ w_fc^T + b_fc, fused log-softmax -> out (fp32)
    mgemm<2, 3, 0, 0, 3><<<gB, 256, 0, stream>>>(
        spB, wfcB, bfc, nullptr, nullptr, out, nullptr, NNODE, 40, 40);
}